// Round 8
// baseline (220.715 us; speedup 1.0000x reference)
//
#include <hip/hip_runtime.h>
#include <hip/hip_bf16.h>
#include <math.h>

#define BQ   2      // batch
#define NN   1024   // seq len
#define DMD  512    // d_model
#define NH   8      // heads
#define DKK  64     // head dim
#define NSEL 5      // NB+1 block values (0..4)
#define NCLS 17     // block-pair classes
#define NP   1344   // padded per-batch capacity (buckets padded to 64)
#define NPT  21     // NP/64 tiles
#define MAXT 3      // max key-tiles per wave in k_attn (ceil(21/8))
#define SSp  1348   // S row stride (shorts): 4-row stride = 2696 dwords = 8 mod 32 -> conflict-free

typedef __attribute__((ext_vector_type(8))) short bf16x8;
typedef __attribute__((ext_vector_type(8))) unsigned short u16x8;
typedef __attribute__((ext_vector_type(4))) float f32x4;

__device__ __forceinline__ int clsOf(int r, int c) { return (r == 0 || c == 0) ? 0 : ((r - 1) * 4 + c); }

__device__ __forceinline__ unsigned short f2bf(float x) {
    __hip_bfloat16 h = __float2bfloat16(x);
    return *reinterpret_cast<unsigned short*>(&h);
}

// ---------------------------------------------------------------- setup (bucketing only)
__global__ __launch_bounds__(256) void k_setup(
    const void* __restrict__ b_seq_r, const void* __restrict__ mask_r,
    int* __restrict__ maskI, int* __restrict__ perm, int* __restrict__ rowc,
    int* __restrict__ startPad, int* __restrict__ maskP)
{
    __shared__ int det[5];
    __shared__ int cnts[BQ][NSEL];
    __shared__ int offs[BQ][NSEL];
    __shared__ int sstart[BQ][NSEL + 1];
    int tid = threadIdx.x;
    if (tid < 5) det[tid] = 0;
    if (tid < BQ * NSEL) { cnts[tid / NSEL][tid % NSEL] = 0; offs[tid / NSEL][tid % NSEL] = 0; }
    __syncthreads();
    const int* b32 = (const int*)b_seq_r;
    const unsigned char* mb = (const unsigned char*)mask_r;
    const int* m32 = (const int*)mask_r;
    if (tid < 64) {
        if (b32[2 * tid + 1] != 0) atomicOr(&det[0], 1);
        if (b32[2 * tid] != 0)     atomicOr(&det[1], 1);
        if (m32[2 * tid + 1] != 0) atomicOr(&det[3], 1);
        if (m32[2 * tid] != 0)     atomicOr(&det[4], 1);
    }
    if ((tid & 3) != 0 && mb[tid] != 0) atomicOr(&det[2], 1);
    __syncthreads();
    int bsI64 = (det[0] == 0 && det[1] != 0);
    int mk = det[2] ? 1 : ((det[3] == 0 && det[4] != 0) ? 2 : 0);

    for (int g = tid; g < BQ * NN; g += 256) {
        int m = (mk == 1) ? (mb[g] != 0) : ((mk == 2) ? (m32[2 * g] != 0) : (m32[g] != 0));
        maskI[g] = m;
        int bs = bsI64 ? b32[2 * g] : b32[g];
        bs = bs < 0 ? 0 : (bs > 4 ? 4 : bs);
        atomicAdd(&cnts[g / NN][bs], 1);
    }
    __syncthreads();
    if (tid == 0) {
        for (int b = 0; b < BQ; b++) {
            int acc = 0;
            for (int c = 0; c < NSEL; c++) {
                sstart[b][c] = acc;
                acc += ((cnts[b][c] + 63) / 64) * 64;
            }
            sstart[b][NSEL] = acc;
            for (int c = 0; c <= NSEL; c++) startPad[b * (NSEL + 1) + c] = sstart[b][c];
        }
    }
    __syncthreads();
    for (int g = tid; g < BQ * NP; g += 256) {
        perm[g] = -1;
        int b = g / NP, sslot = g % NP;
        int c = 0;
        for (int cc = 1; cc < NSEL; cc++) if (sslot >= sstart[b][cc]) c = cc;
        rowc[g] = c;
    }
    __syncthreads();
    for (int g = tid; g < BQ * NN; g += 256) {
        int b = g / NN, n = g % NN;
        int bs = bsI64 ? b32[2 * g] : b32[g];
        bs = bs < 0 ? 0 : (bs > 4 ? 4 : bs);
        int pos = sstart[b][bs] + atomicAdd(&offs[b][bs], 1);
        perm[b * NP + pos] = n;
    }
    __syncthreads();
    for (int g = tid; g < BQ * NP; g += 256) {
        int tok = perm[g];
        maskP[g] = (tok < 0) ? 2 : maskI[(g / NP) * NN + tok];
    }
}

// ---------------------------------------------------------------- prep: cast lin->Lt (960 blocks) + wmix (272 blocks)
__global__ __launch_bounds__(256) void k_prep(
    const float* __restrict__ lr, unsigned short* __restrict__ Lt,
    const float* __restrict__ W1, const float* __restrict__ W2,
    const float* __restrict__ al1, const float* __restrict__ al2,
    unsigned short* __restrict__ W1bt, unsigned short* __restrict__ W2bt)
{
    int bx = blockIdx.x;
    int tid = threadIdx.x;
    if (bx < 960) {
        int ts = bx >> 6, rem = bx & 63;
        int kt = rem >> 3, nt = rem & 7;
        const float* src = lr + (size_t)ts * DMD * 512;
        unsigned short* dst = Lt + (size_t)ts * DMD * 512;
        __shared__ float Tf[64][68];
        int r = tid >> 2, c4 = tid & 3;
#pragma unroll
        for (int i = 0; i < 4; i++) {
            float4 v = *(const float4*)&src[(size_t)(kt * 64 + r) * 512 + nt * 64 + c4 * 16 + i * 4];
            *(float4*)&Tf[r][c4 * 16 + i * 4] = v;
        }
        __syncthreads();
        unsigned short tmp[16];
#pragma unroll
        for (int i = 0; i < 16; i++) tmp[i] = f2bf(Tf[c4 * 16 + i][r]);
        u16x8 o0, o1;
#pragma unroll
        for (int i = 0; i < 8; i++) { o0[i] = tmp[i]; o1[i] = tmp[8 + i]; }
        unsigned short* dp = &dst[(size_t)(nt * 64 + r) * 512 + kt * 64 + c4 * 16];
        *(u16x8*)&dp[0] = o0;
        *(u16x8*)&dp[8] = o1;
    } else {
        int bid = bx - 960;
        int w = bid / (NCLS * NH);
        int rem = bid % (NCLS * NH);
        int c = rem / NH, h = rem % NH;
        const float* W = w ? W2 : W1;
        const float* a = w ? al2 : al1;
        unsigned short* outp = (w ? W2bt : W1bt) + (((size_t)c * NH + h) << 12);
        float vals[4], mx = -1e30f;
#pragma unroll
        for (int bb = 0; bb < 4; bb++) { vals[bb] = a[(c * 4 + bb) * NH + h]; mx = fmaxf(mx, vals[bb]); }
        float ssum = 0.f;
#pragma unroll
        for (int bb = 0; bb < 4; bb++) { vals[bb] = __expf(vals[bb] - mx); ssum += vals[bb]; }
        float inv = 1.0f / ssum;
        float s0 = vals[0] * inv, s1 = vals[1] * inv, s2 = vals[2] * inv, s3 = vals[3] * inv;
        const float* p0 = W + (size_t)(0 * NH + h) * 4096;
        const float* p1 = W + (size_t)(1 * NH + h) * 4096;
        const float* p2 = W + (size_t)(2 * NH + h) * 4096;
        const float* p3 = W + (size_t)(3 * NH + h) * 4096;
        for (int e = tid; e < 4096; e += 256) {
            float v = s0 * p0[e] + s1 * p1[e] + s2 * p2[e] + s3 * p3[e];
            int mm = e >> 6, nn = e & 63;
            outp[nn * 64 + mm] = f2bf(v);     // transposed store
        }
    }
}

// ---------------------------------------------------------------- bucketed QKV projection, MFMA bf16
__global__ __launch_bounds__(256) void k_proj(
    const float* __restrict__ qr, const float* __restrict__ kr, const float* __restrict__ vr,
    const unsigned short* __restrict__ Lt,
    const int* __restrict__ perm, const int* __restrict__ rowc, const int* __restrict__ startPad,
    unsigned short* __restrict__ Qb, unsigned short* __restrict__ Kb, unsigned short* __restrict__ Vb)
{
    int ti = blockIdx.x;
    int qtr = blockIdx.y;
    int bt = blockIdx.z;
    int b = bt / 3, t = bt % 3;
    int nTot = startPad[b * (NSEL + 1) + NSEL];
    if (ti * 64 >= nTot) return;
    int sel = rowc[b * NP + ti * 64];
    const float* X = (t == 0) ? qr : ((t == 1) ? kr : vr);
    const unsigned short* L = Lt + (size_t)(t * NSEL + sel) * DMD * 512;   // [n][k] bf16

    __shared__ __align__(16) unsigned short Xb[64][72];
    __shared__ __align__(16) unsigned short Lb[128][72];
    __shared__ int toks[64];

    int tid = threadIdx.x;
    int wave = tid >> 6, lane = tid & 63;
    int m = lane & 15, q = lane >> 4;
    if (tid < 64) toks[tid] = perm[b * NP + ti * 64 + tid];
    f32x4 acc[4][2];
#pragma unroll
    for (int mt = 0; mt < 4; mt++) { acc[mt][0] = {0, 0, 0, 0}; acc[mt][1] = {0, 0, 0, 0}; }
    __syncthreads();

    for (int kb = 0; kb < DMD; kb += 64) {
        {
            int r = tid >> 2, c0 = (tid & 3) * 16;
            int tok = toks[r];
            unsigned short tmp[16];
            if (tok >= 0) {
                const float* xp = &X[((size_t)b * NN + tok) * DMD + kb + c0];
#pragma unroll
                for (int i = 0; i < 16; i += 4) {
                    float4 v = *(const float4*)&xp[i];
                    tmp[i] = f2bf(v.x); tmp[i + 1] = f2bf(v.y);
                    tmp[i + 2] = f2bf(v.z); tmp[i + 3] = f2bf(v.w);
                }
            } else {
#pragma unroll
                for (int i = 0; i < 16; i++) tmp[i] = 0;
            }
            u16x8 o0, o1;
#pragma unroll
            for (int i = 0; i < 8; i++) { o0[i] = tmp[i]; o1[i] = tmp[8 + i]; }
            *(u16x8*)&Xb[r][c0] = o0;
            *(u16x8*)&Xb[r][c0 + 8] = o1;
        }
        {
            int n = tid >> 1, hf = tid & 1;
            const unsigned short* lp = &L[(size_t)(qtr * 128 + n) * 512 + kb + hf * 32];
#pragma unroll
            for (int s = 0; s < 4; s++)
                *(u16x8*)&Lb[n][hf * 32 + s * 8] = *(const u16x8*)&lp[s * 8];
        }
        __syncthreads();
#pragma unroll
        for (int kc = 0; kc < 64; kc += 32) {
            bf16x8 bf0 = *(const bf16x8*)&Lb[wave * 32 + m][kc + q * 8];
            bf16x8 bf1 = *(const bf16x8*)&Lb[wave * 32 + 16 + m][kc + q * 8];
#pragma unroll
            for (int mt = 0; mt < 4; mt++) {
                bf16x8 a = *(const bf16x8*)&Xb[mt * 16 + m][kc + q * 8];
                acc[mt][0] = __builtin_amdgcn_mfma_f32_16x16x32_bf16(a, bf0, acc[mt][0], 0, 0, 0);
                acc[mt][1] = __builtin_amdgcn_mfma_f32_16x16x32_bf16(a, bf1, acc[mt][1], 0, 0, 0);
            }
        }
        __syncthreads();
    }

    unsigned short* O = (t == 0) ? Qb : ((t == 1) ? Kb : Vb);
#pragma unroll
    for (int mt = 0; mt < 4; mt++)
#pragma unroll
        for (int nt = 0; nt < 2; nt++)
#pragma unroll
            for (int g = 0; g < 4; g++) {
                int i = mt * 16 + q * 4 + g;
                int hk = qtr * 128 + wave * 32 + nt * 16 + m;
                int h = hk >> 6, k0 = hk & 63;
                O[(((size_t)b * NH + h) * NP + ti * 64 + i) * 64 + k0] = f2bf(acc[mt][nt][g]);
            }
}

// ---------------------------------------------------------------- Q2/V2t precompute, MFMA (XCD-swizzled)
__global__ __launch_bounds__(256) void k_qv2(
    const unsigned short* __restrict__ Qb, const unsigned short* __restrict__ Vb,
    const unsigned short* __restrict__ W1bt, const unsigned short* __restrict__ W2bt,
    const int* __restrict__ rowc, const int* __restrict__ startPad,
    unsigned short* __restrict__ Q2, unsigned short* __restrict__ V2t)
{
    // 3360 blocks = 8 XCDs x 4 zz x 105 (cv,ti): same-XCD blocks share zz
    int bid = blockIdx.x;
    int xcd = bid & 7, local = bid >> 3;          // 0..419
    int zz = xcd * 4 + local / 105;
    int rem = local % 105;
    int cv = rem / 21, ti = rem % 21;
    int type = zz >> 4, bh = zz & 15;
    int b = bh >> 3, h = bh & 7;
    int nTot = startPad[b * (NSEL + 1) + NSEL];
    if (ti * 64 >= nTot) return;
    int tb = rowc[b * NP + ti * 64];
    int tid = threadIdx.x;
    int wave = tid >> 6, lane = tid & 63;
    int m = lane & 15, q = lane >> 4;

    const unsigned short *A, *B;
    unsigned short* C;
    size_t cRow;
    if (type == 0) {
        int cls = clsOf(tb, cv);
        A = Qb + ((size_t)bh * NP + ti * 64) * 64;
        B = W1bt + (((size_t)cls * NH + h) << 12);
        C = Q2 + (((size_t)cv * 16 + bh) * NP + ti * 64) * 64;
        cRow = 64;
    } else {
        int cls = clsOf(cv, tb);
        A = W2bt + (((size_t)cls * NH + h) << 12);
        B = Vb + ((size_t)bh * NP + ti * 64) * 64;
        C = V2t + ((size_t)cv * 16 + bh) * 64 * NP + ti * 64;
        cRow = NP;
    }
    const unsigned short* bp = B + (size_t)(wave * 16 + m) * 64 + q * 8;
    bf16x8 b0 = *(const bf16x8*)bp;
    bf16x8 b1 = *(const bf16x8*)(bp + 32);
#pragma unroll
    for (int mb = 0; mb < 4; mb++) {
        const unsigned short* ap = A + (size_t)(mb * 16 + m) * 64 + q * 8;
        bf16x8 a0 = *(const bf16x8*)ap;
        bf16x8 a1 = *(const bf16x8*)(ap + 32);
        f32x4 acc = {0.f, 0.f, 0.f, 0.f};
        acc = __builtin_amdgcn_mfma_f32_16x16x32_bf16(a0, b0, acc, 0, 0, 0);
        acc = __builtin_amdgcn_mfma_f32_16x16x32_bf16(a1, b1, acc, 0, 0, 0);
#pragma unroll
        for (int g = 0; g < 4; g++)
            C[(size_t)(mb * 16 + q * 4 + g) * cRow + wave * 16 + m] = f2bf(acc[g]);
    }
}

// ---------------------------------------------------------------- fused attention: 512 threads, XCD-swizzled
// 1344 blocks = 8 XCDs x 2 bh x 84 i-tiles: per-XCD L2 set ~3.8 MB (fits 4 MB).
__global__ __launch_bounds__(512, 6) void k_attn(
    const unsigned short* __restrict__ Q2, const unsigned short* __restrict__ Kb,
    const unsigned short* __restrict__ V2t,
    const int* __restrict__ perm, const int* __restrict__ rowc, const int* __restrict__ startPad,
    const int* __restrict__ maskI, const int* __restrict__ maskP,
    float* __restrict__ out)
{
    int bid = blockIdx.x;
    int xcd = bid & 7, local = bid >> 3;          // 0..167
    int bh = xcd * 2 + (local >= 84 ? 1 : 0);
    int it = (local >= 84) ? (local - 84) : local;
    int b = bh >> 3, h = bh & 7;
    int nTot = startPad[b * (NSEL + 1) + NSEL];
    int i0 = it * 16;
    if (i0 >= nTot) return;
    int r = rowc[b * NP + i0];
    int tiles = nTot >> 6;

    __shared__ unsigned short S[16][SSp];        // 43136 B: P (bf16)
    __shared__ float wred[8][16];
    __shared__ float wsum[8][16];
    __shared__ float pbuf[2][16][64];            // 8192 B: PV partials (j-parity halves)
    __shared__ int tilec[NPT];
    __shared__ int mrow[16];
    __shared__ int toki[16];

    int tid = threadIdx.x;
    int wave = tid >> 6, lane = tid & 63;
    int m = lane & 15, q = lane >> 4;

    const int* permB = perm + b * NP;
    const unsigned short* KbB = Kb + (size_t)bh * NP * 64;
    const unsigned short* Q2B = Q2 + (size_t)bh * NP * 64;             // + c*16*NP*64
    const unsigned short* V2B = V2t + ((size_t)r * 16 + bh) * 64 * NP; // [k][jp]
    const int* maskPB = maskP + b * NP;

    if (tid < NPT) tilec[tid] = rowc[b * NP + tid * 64];
    else if (tid >= 64 && tid < 80) {
        int rr = tid - 64;
        int tok = permB[i0 + rr];
        toki[rr] = tok;
        mrow[rr] = (tok >= 0) ? maskI[b * NN + tok] : 0;
    }
    __syncthreads();

    // ---- phase 1: scores in registers (wave stride 8 over j-tiles)
    float sarr[MAXT][4][4];
    float lmax[4] = {-INFINITY, -INFINITY, -INFINITY, -INFINITY};
    int mrow4[4];
#pragma unroll
    for (int g = 0; g < 4; g++) mrow4[g] = mrow[q * 4 + g];

#pragma unroll
    for (int tt = 0; tt < MAXT; tt++) {
        int jt = wave + tt * 8;
        bool valid = (jt < tiles);
        int jts = valid ? jt : 0;
        int c = tilec[jts];
        int jb = jts * 64;
        const unsigned short* qa = Q2B + (size_t)c * 16 * NP * 64 + (size_t)(i0 + m) * 64 + q * 8;
        bf16x8 a0 = *(const bf16x8*)qa;
        bf16x8 a1 = *(const bf16x8*)(qa + 32);
#pragma unroll
        for (int nb = 0; nb < 4; nb++) {
            int j = jb + nb * 16 + m;
            const unsigned short* kb = &KbB[(size_t)j * 64 + q * 8];
            bf16x8 b0 = *(const bf16x8*)kb;
            bf16x8 b1 = *(const bf16x8*)(kb + 32);
            f32x4 acc = {0.f, 0.f, 0.f, 0.f};
            acc = __builtin_amdgcn_mfma_f32_16x16x32_bf16(a0, b0, acc, 0, 0, 0);
            acc = __builtin_amdgcn_mfma_f32_16x16x32_bf16(a1, b1, acc, 0, 0, 0);
            int mj = maskPB[j];
#pragma unroll
            for (int g = 0; g < 4; g++) {
                float sv;
                if (!valid || mj == 2)   sv = -INFINITY;      // padding / no tile
                else if (mrow4[g] && mj) sv = acc[g] * 0.125f;
                else                     sv = -1e30f;         // reference's masked value
                sarr[tt][nb][g] = sv;
                lmax[g] = fmaxf(lmax[g], sv);
            }
        }
    }
#pragma unroll
    for (int g = 0; g < 4; g++) {
        float v = lmax[g];
#pragma unroll
        for (int o = 1; o < 16; o <<= 1) v = fmaxf(v, __shfl_xor(v, o));
        lmax[g] = v;
    }
    if (m == 0) {
#pragma unroll
        for (int g = 0; g < 4; g++) wred[wave][q * 4 + g] = lmax[g];
    }
    __syncthreads();

    // ---- phase 2: exp in regs, single P write, row sums (normalization deferred)
    float mx4[4], lsum[4] = {0.f, 0.f, 0.f, 0.f};
#pragma unroll
    for (int g = 0; g < 4; g++) {
        int i = q * 4 + g;
        float v = wred[0][i];
#pragma unroll
        for (int w2 = 1; w2 < 8; w2++) v = fmaxf(v, wred[w2][i]);
        mx4[g] = v;
    }
#pragma unroll
    for (int tt = 0; tt < MAXT; tt++) {
        int jt = wave + tt * 8;
        bool valid = (jt < tiles);
        int jb = jt * 64;
#pragma unroll
        for (int nb = 0; nb < 4; nb++) {
            int j = jb + nb * 16 + m;
#pragma unroll
            for (int g = 0; g < 4; g++) {
                float p = __expf(sarr[tt][nb][g] - mx4[g]);   // -inf -> 0
                lsum[g] += p;
                if (valid) S[q * 4 + g][j] = f2bf(p);
            }
        }
    }
#pragma unroll
    for (int g = 0; g < 4; g++) {
        float v = lsum[g];
#pragma unroll
        for (int o = 1; o < 16; o <<= 1) v += __shfl_xor(v, o);
        lsum[g] = v;
    }
    if (m == 0) {
#pragma unroll
        for (int g = 0; g < 4; g++) wsum[wave][q * 4 + g] = lsum[g];
    }
    __syncthreads();

    // ---- phase 3: out = P . V2t^T ; wave (kw,p): k-subtile kw, j-parity p
    {
        int kw = wave & 3, p = wave >> 2;
        int db = kw * 16;
        f32x4 ae = {0.f, 0.f, 0.f, 0.f};
        f32x4 ao = {0.f, 0.f, 0.f, 0.f};
        for (int jt = p; jt < tiles; jt += 2) {
            int jb = jt * 64;
            bf16x8 a0 = *(const bf16x8*)&S[m][jb + q * 8];
            bf16x8 a1 = *(const bf16x8*)&S[m][jb + 32 + q * 8];
            const unsigned short* vb = V2B + (size_t)(db + m) * NP + jb + q * 8;
            bf16x8 b0 = *(const bf16x8*)vb;
            bf16x8 b1 = *(const bf16x8*)(vb + 32);
            ae = __builtin_amdgcn_mfma_f32_16x16x32_bf16(a0, b0, ae, 0, 0, 0);
            ao = __builtin_amdgcn_mfma_f32_16x16x32_bf16(a1, b1, ao, 0, 0, 0);
        }
#pragma unroll
        for (int g = 0; g < 4; g++)
            pbuf[p][q * 4 + g][db + m] = ae[g] + ao[g];
    }
    __syncthreads();

    // ---- epilogue: combine parities, normalize, store (1024 outputs / 512 threads)
    for (int idx = tid; idx < 16 * 64; idx += 512) {
        int i = idx >> 6, k = idx & 63;
        int tok = toki[i];
        if (tok >= 0) {
            float s = wsum[0][i] + wsum[1][i] + wsum[2][i] + wsum[3][i]
                    + wsum[4][i] + wsum[5][i] + wsum[6][i] + wsum[7][i];
            float v = pbuf[0][i][k] + pbuf[1][i][k];
            out[((size_t)b * NN + tok) * (NH * DKK) + h * DKK + k] = v / s;
        }
    }
}

// ---------------------------------------------------------------- launch
extern "C" void kernel_launch(void* const* d_in, const int* in_sizes, int n_in,
                              void* d_out, int out_size, void* d_ws, size_t ws_size,
                              hipStream_t stream)
{
    const float* qr  = (const float*)d_in[0];
    const float* kr  = (const float*)d_in[1];
    const float* vr  = (const float*)d_in[2];
    const void* bsr  = d_in[3];
    const void* mkr  = d_in[4];
    const float* lr  = (const float*)d_in[5];
    const float* w1r = (const float*)d_in[6];
    const float* a1r = (const float*)d_in[7];
    const float* w2r = (const float*)d_in[8];
    const float* a2r = (const float*)d_in[9];
    float* out = (float*)d_out;

    char* w = (char*)d_ws;
    int* maskI    = (int*)w;
    int* perm     = maskI + BQ * NN;
    int* rowc     = perm + BQ * NP;
    int* startPad = rowc + BQ * NP;
    int* maskP    = startPad + 12;
    unsigned short* W1bt = (unsigned short*)(w + 65536);
    unsigned short* W2bt = W1bt + (size_t)NCLS * NH * 4096;
    unsigned short* Qb   = (unsigned short*)(w + 2359296);
    unsigned short* Kb   = Qb + (size_t)BQ * NH * NP * 64;
    unsigned short* Vb   = Kb + (size_t)BQ * NH * NP * 64;
    unsigned short* Lt   = (unsigned short*)(w + 10616832);          // dead after k_proj
    unsigned short* Q2   = Lt;                                       // aliases Lt (stream-ordered safe)
    unsigned short* V2t  = (unsigned short*)(w + 24379392);          // total ~38.1 MB

    hipLaunchKernelGGL(k_setup, dim3(1), dim3(256), 0, stream,
                       bsr, mkr, maskI, perm, rowc, startPad, maskP);
    hipLaunchKernelGGL(k_prep, dim3(960 + 2 * NCLS * NH), dim3(256), 0, stream,
                       lr, Lt, w1r, w2r, a1r, a2r, W1bt, W2bt);
    hipLaunchKernelGGL(k_proj, dim3(NPT, 4, 6), dim3(256), 0, stream,
                       qr, kr, vr, Lt, perm, rowc, startPad, Qb, Kb, Vb);
    hipLaunchKernelGGL(k_qv2, dim3(8 * 4 * 105), dim3(256), 0, stream,
                       Qb, Vb, W1bt, W2bt, rowc, startPad, Q2, V2t);
    hipLaunchKernelGGL(k_attn, dim3(8 * 2 * 84), dim3(512), 0, stream,
                       Q2, Kb, V2t, perm, rowc, startPad, maskI, maskP, out);
}

// Round 9
// 208.862 us; speedup vs baseline: 1.0567x; 1.0567x over previous
//
#include <hip/hip_runtime.h>
#include <hip/hip_bf16.h>
#include <math.h>

#define BQ   2      // batch
#define NN   1024   // seq len
#define DMD  512    // d_model
#define NH   8      // heads
#define DKK  64     // head dim
#define NSEL 5      // NB+1 block values (0..4)
#define NCLS 17     // block-pair classes
#define NP   1344   // padded per-batch capacity (buckets padded to 64)
#define NPT  21     // NP/64 tiles
#define MAXT 3      // max key-tiles per wave in k_attn (ceil(21/8))
#define SSp  1348   // S row stride (shorts): conflict-free

typedef __attribute__((ext_vector_type(8))) short bf16x8;
typedef __attribute__((ext_vector_type(8))) unsigned short u16x8;
typedef __attribute__((ext_vector_type(4))) float f32x4;

__device__ __forceinline__ int clsOf(int r, int c) { return (r == 0 || c == 0) ? 0 : ((r - 1) * 4 + c); }

__device__ __forceinline__ unsigned short f2bf(float x) {
    __hip_bfloat16 h = __float2bfloat16(x);
    return *reinterpret_cast<unsigned short*>(&h);
}

// ---------------------------------------------------------------- setup (bucketing only)
__global__ __launch_bounds__(256) void k_setup(
    const void* __restrict__ b_seq_r, const void* __restrict__ mask_r,
    int* __restrict__ maskI, int* __restrict__ perm, int* __restrict__ rowc,
    int* __restrict__ startPad, int* __restrict__ maskP)
{
    __shared__ int det[5];
    __shared__ int cnts[BQ][NSEL];
    __shared__ int offs[BQ][NSEL];
    __shared__ int sstart[BQ][NSEL + 1];
    int tid = threadIdx.x;
    if (tid < 5) det[tid] = 0;
    if (tid < BQ * NSEL) { cnts[tid / NSEL][tid % NSEL] = 0; offs[tid / NSEL][tid % NSEL] = 0; }
    __syncthreads();
    const int* b32 = (const int*)b_seq_r;
    const unsigned char* mb = (const unsigned char*)mask_r;
    const int* m32 = (const int*)mask_r;
    if (tid < 64) {
        if (b32[2 * tid + 1] != 0) atomicOr(&det[0], 1);
        if (b32[2 * tid] != 0)     atomicOr(&det[1], 1);
        if (m32[2 * tid + 1] != 0) atomicOr(&det[3], 1);
        if (m32[2 * tid] != 0)     atomicOr(&det[4], 1);
    }
    if ((tid & 3) != 0 && mb[tid] != 0) atomicOr(&det[2], 1);
    __syncthreads();
    int bsI64 = (det[0] == 0 && det[1] != 0);
    int mk = det[2] ? 1 : ((det[3] == 0 && det[4] != 0) ? 2 : 0);

    for (int g = tid; g < BQ * NN; g += 256) {
        int m = (mk == 1) ? (mb[g] != 0) : ((mk == 2) ? (m32[2 * g] != 0) : (m32[g] != 0));
        maskI[g] = m;
        int bs = bsI64 ? b32[2 * g] : b32[g];
        bs = bs < 0 ? 0 : (bs > 4 ? 4 : bs);
        atomicAdd(&cnts[g / NN][bs], 1);
    }
    __syncthreads();
    if (tid == 0) {
        for (int b = 0; b < BQ; b++) {
            int acc = 0;
            for (int c = 0; c < NSEL; c++) {
                sstart[b][c] = acc;
                acc += ((cnts[b][c] + 63) / 64) * 64;
            }
            sstart[b][NSEL] = acc;
            for (int c = 0; c <= NSEL; c++) startPad[b * (NSEL + 1) + c] = sstart[b][c];
        }
    }
    __syncthreads();
    for (int g = tid; g < BQ * NP; g += 256) {
        perm[g] = -1;
        int b = g / NP, sslot = g % NP;
        int c = 0;
        for (int cc = 1; cc < NSEL; cc++) if (sslot >= sstart[b][cc]) c = cc;
        rowc[g] = c;
    }
    __syncthreads();
    for (int g = tid; g < BQ * NN; g += 256) {
        int b = g / NN, n = g % NN;
        int bs = bsI64 ? b32[2 * g] : b32[g];
        bs = bs < 0 ? 0 : (bs > 4 ? 4 : bs);
        int pos = sstart[b][bs] + atomicAdd(&offs[b][bs], 1);
        perm[b * NP + pos] = n;
    }
    __syncthreads();
    for (int g = tid; g < BQ * NP; g += 256) {
        int tok = perm[g];
        maskP[g] = (tok < 0) ? 2 : maskI[(g / NP) * NN + tok];
    }
}

// ---------------------------------------------------------------- prep: lin cast (960) + wmix (272) + qkv cast (96)
__global__ __launch_bounds__(256) void k_prep(
    const float* __restrict__ lr, unsigned short* __restrict__ Lt,
    const float* __restrict__ W1, const float* __restrict__ W2,
    const float* __restrict__ al1, const float* __restrict__ al2,
    unsigned short* __restrict__ W1bt, unsigned short* __restrict__ W2bt,
    const float* __restrict__ qr, const float* __restrict__ kr, const float* __restrict__ vr,
    unsigned short* __restrict__ Xc)
{
    int bx = blockIdx.x;
    int tid = threadIdx.x;
    if (bx < 960) {
        int ts = bx >> 6, rem = bx & 63;
        int kt = rem >> 3, nt = rem & 7;
        const float* src = lr + (size_t)ts * DMD * 512;
        unsigned short* dst = Lt + (size_t)ts * DMD * 512;
        __shared__ float Tf[64][68];
        int r = tid >> 2, c4 = tid & 3;
#pragma unroll
        for (int i = 0; i < 4; i++) {
            float4 v = *(const float4*)&src[(size_t)(kt * 64 + r) * 512 + nt * 64 + c4 * 16 + i * 4];
            *(float4*)&Tf[r][c4 * 16 + i * 4] = v;
        }
        __syncthreads();
        unsigned short tmp[16];
#pragma unroll
        for (int i = 0; i < 16; i++) tmp[i] = f2bf(Tf[c4 * 16 + i][r]);
        u16x8 o0, o1;
#pragma unroll
        for (int i = 0; i < 8; i++) { o0[i] = tmp[i]; o1[i] = tmp[8 + i]; }
        unsigned short* dp = &dst[(size_t)(nt * 64 + r) * 512 + kt * 64 + c4 * 16];
        *(u16x8*)&dp[0] = o0;
        *(u16x8*)&dp[8] = o1;
    } else if (bx < 960 + 2 * NCLS * NH) {
        int bid = bx - 960;
        int w = bid / (NCLS * NH);
        int rem = bid % (NCLS * NH);
        int c = rem / NH, h = rem % NH;
        const float* W = w ? W2 : W1;
        const float* a = w ? al2 : al1;
        unsigned short* outp = (w ? W2bt : W1bt) + (((size_t)c * NH + h) << 12);
        float vals[4], mx = -1e30f;
#pragma unroll
        for (int bb = 0; bb < 4; bb++) { vals[bb] = a[(c * 4 + bb) * NH + h]; mx = fmaxf(mx, vals[bb]); }
        float ssum = 0.f;
#pragma unroll
        for (int bb = 0; bb < 4; bb++) { vals[bb] = __expf(vals[bb] - mx); ssum += vals[bb]; }
        float inv = 1.0f / ssum;
        float s0 = vals[0] * inv, s1 = vals[1] * inv, s2 = vals[2] * inv, s3 = vals[3] * inv;
        const float* p0 = W + (size_t)(0 * NH + h) * 4096;
        const float* p1 = W + (size_t)(1 * NH + h) * 4096;
        const float* p2 = W + (size_t)(2 * NH + h) * 4096;
        const float* p3 = W + (size_t)(3 * NH + h) * 4096;
        for (int e = tid; e < 4096; e += 256) {
            float v = s0 * p0[e] + s1 * p1[e] + s2 * p2[e] + s3 * p3[e];
            int mm = e >> 6, nn = e & 63;
            outp[nn * 64 + mm] = f2bf(v);     // transposed store
        }
    } else {
        // cast q/k/v -> Xc bf16 [t][b][n][512]
        int bid = bx - (960 + 2 * NCLS * NH);   // 0..95
        int t = bid / 32, rem = bid % 32;
        int b = rem / 16, rg = rem % 16;
        int row = tid >> 2, part = tid & 3;
        const float* X = (t == 0) ? qr : ((t == 1) ? kr : vr);
        const float* src = X + ((size_t)b * NN + rg * 64 + row) * DMD + part * 128;
        unsigned short* dst = Xc + (((size_t)t * BQ + b) * NN + rg * 64 + row) * DMD + part * 128;
#pragma unroll
        for (int i = 0; i < 128; i += 8) {
            float4 v0 = *(const float4*)&src[i];
            float4 v1 = *(const float4*)&src[i + 4];
            u16x8 o;
            o[0] = f2bf(v0.x); o[1] = f2bf(v0.y); o[2] = f2bf(v0.z); o[3] = f2bf(v0.w);
            o[4] = f2bf(v1.x); o[5] = f2bf(v1.y); o[6] = f2bf(v1.z); o[7] = f2bf(v1.w);
            *(u16x8*)&dst[i] = o;
        }
    }
}

// ---------------------------------------------------------------- bucketed QKV projection, MFMA bf16 (XCD-grouped)
// 672 blocks: xcd = bid&7; same (t,qtr) group pinned to one XCD -> Lt slices (5x128 KB) stay L2-resident.
__global__ __launch_bounds__(256) void k_proj(
    const unsigned short* __restrict__ Xc,
    const unsigned short* __restrict__ Lt,
    const int* __restrict__ perm, const int* __restrict__ rowc, const int* __restrict__ startPad,
    unsigned short* __restrict__ Qb, unsigned short* __restrict__ Kb, unsigned short* __restrict__ Vb)
{
    int bid = blockIdx.x;
    int xcd = bid & 7, local = bid >> 3;          // 0..83
    int g;
    if (local < 42) g = xcd;
    else { if (xcd >= 4) return; g = xcd + 8; }
    if (g >= 12) return;
    int idx = local % 42;
    int t = g >> 2, qtr = g & 3;
    int ti = idx >> 1, b = idx & 1;

    int nTot = startPad[b * (NSEL + 1) + NSEL];
    if (ti * 64 >= nTot) return;
    int sel = rowc[b * NP + ti * 64];
    const unsigned short* XcT = Xc + ((size_t)t * BQ + b) * NN * DMD;
    const unsigned short* L = Lt + (size_t)(t * NSEL + sel) * DMD * 512;   // [n][k] bf16

    __shared__ __align__(16) unsigned short Xb[64][72];
    __shared__ __align__(16) unsigned short Lb[128][72];
    __shared__ int toks[64];

    int tid = threadIdx.x;
    int wave = tid >> 6, lane = tid & 63;
    int m = lane & 15, q = lane >> 4;
    if (tid < 64) toks[tid] = perm[b * NP + ti * 64 + tid];
    f32x4 acc[4][2];
#pragma unroll
    for (int mt = 0; mt < 4; mt++) { acc[mt][0] = {0, 0, 0, 0}; acc[mt][1] = {0, 0, 0, 0}; }
    __syncthreads();

    for (int kb = 0; kb < DMD; kb += 64) {
        {
            int r = tid >> 2, c0 = (tid & 3) * 16;
            int tok = toks[r];
            u16x8 o0 = {0, 0, 0, 0, 0, 0, 0, 0}, o1 = {0, 0, 0, 0, 0, 0, 0, 0};
            if (tok >= 0) {
                const unsigned short* xp = &XcT[(size_t)tok * DMD + kb + c0];
                o0 = *(const u16x8*)xp;
                o1 = *(const u16x8*)(xp + 8);
            }
            *(u16x8*)&Xb[r][c0] = o0;
            *(u16x8*)&Xb[r][c0 + 8] = o1;
        }
        {
            int n = tid >> 1, hf = tid & 1;
            const unsigned short* lp = &L[(size_t)(qtr * 128 + n) * 512 + kb + hf * 32];
#pragma unroll
            for (int s = 0; s < 4; s++)
                *(u16x8*)&Lb[n][hf * 32 + s * 8] = *(const u16x8*)&lp[s * 8];
        }
        __syncthreads();
#pragma unroll
        for (int kc = 0; kc < 64; kc += 32) {
            bf16x8 bf0 = *(const bf16x8*)&Lb[wave * 32 + m][kc + q * 8];
            bf16x8 bf1 = *(const bf16x8*)&Lb[wave * 32 + 16 + m][kc + q * 8];
#pragma unroll
            for (int mt = 0; mt < 4; mt++) {
                bf16x8 a = *(const bf16x8*)&Xb[mt * 16 + m][kc + q * 8];
                acc[mt][0] = __builtin_amdgcn_mfma_f32_16x16x32_bf16(a, bf0, acc[mt][0], 0, 0, 0);
                acc[mt][1] = __builtin_amdgcn_mfma_f32_16x16x32_bf16(a, bf1, acc[mt][1], 0, 0, 0);
            }
        }
        __syncthreads();
    }

    unsigned short* O = (t == 0) ? Qb : ((t == 1) ? Kb : Vb);
#pragma unroll
    for (int mt = 0; mt < 4; mt++)
#pragma unroll
        for (int nt = 0; nt < 2; nt++)
#pragma unroll
            for (int gg = 0; gg < 4; gg++) {
                int i = mt * 16 + q * 4 + gg;
                int hk = qtr * 128 + wave * 32 + nt * 16 + m;
                int h = hk >> 6, k0 = hk & 63;
                O[(((size_t)b * NH + h) * NP + ti * 64 + i) * 64 + k0] = f2bf(acc[mt][nt][gg]);
            }
}

// ---------------------------------------------------------------- Q2/V2t precompute, MFMA (XCD-swizzled)
__global__ __launch_bounds__(256) void k_qv2(
    const unsigned short* __restrict__ Qb, const unsigned short* __restrict__ Vb,
    const unsigned short* __restrict__ W1bt, const unsigned short* __restrict__ W2bt,
    const int* __restrict__ rowc, const int* __restrict__ startPad,
    unsigned short* __restrict__ Q2, unsigned short* __restrict__ V2t)
{
    // 3360 blocks = 8 XCDs x 4 zz x 105 (cv,ti): same-XCD blocks share zz
    int bid = blockIdx.x;
    int xcd = bid & 7, local = bid >> 3;          // 0..419
    int zz = xcd * 4 + local / 105;
    int rem = local % 105;
    int cv = rem / 21, ti = rem % 21;
    int type = zz >> 4, bh = zz & 15;
    int b = bh >> 3, h = bh & 7;
    int nTot = startPad[b * (NSEL + 1) + NSEL];
    if (ti * 64 >= nTot) return;
    int tb = rowc[b * NP + ti * 64];
    int tid = threadIdx.x;
    int wave = tid >> 6, lane = tid & 63;
    int m = lane & 15, q = lane >> 4;

    const unsigned short *A, *B;
    unsigned short* C;
    size_t cRow;
    if (type == 0) {
        int cls = clsOf(tb, cv);
        A = Qb + ((size_t)bh * NP + ti * 64) * 64;
        B = W1bt + (((size_t)cls * NH + h) << 12);
        C = Q2 + (((size_t)cv * 16 + bh) * NP + ti * 64) * 64;
        cRow = 64;
    } else {
        int cls = clsOf(cv, tb);
        A = W2bt + (((size_t)cls * NH + h) << 12);
        B = Vb + ((size_t)bh * NP + ti * 64) * 64;
        C = V2t + ((size_t)cv * 16 + bh) * 64 * NP + ti * 64;
        cRow = NP;
    }
    const unsigned short* bp = B + (size_t)(wave * 16 + m) * 64 + q * 8;
    bf16x8 b0 = *(const bf16x8*)bp;
    bf16x8 b1 = *(const bf16x8*)(bp + 32);
#pragma unroll
    for (int mb = 0; mb < 4; mb++) {
        const unsigned short* ap = A + (size_t)(mb * 16 + m) * 64 + q * 8;
        bf16x8 a0 = *(const bf16x8*)ap;
        bf16x8 a1 = *(const bf16x8*)(ap + 32);
        f32x4 acc = {0.f, 0.f, 0.f, 0.f};
        acc = __builtin_amdgcn_mfma_f32_16x16x32_bf16(a0, b0, acc, 0, 0, 0);
        acc = __builtin_amdgcn_mfma_f32_16x16x32_bf16(a1, b1, acc, 0, 0, 0);
#pragma unroll
        for (int g = 0; g < 4; g++)
            C[(size_t)(mb * 16 + q * 4 + g) * cRow + wave * 16 + m] = f2bf(acc[g]);
    }
}

// ---------------------------------------------------------------- fused attention: 512 threads, XCD-swizzled
// launch_bounds (512,4): VGPR cap 128 (demand ~110) -> NO SPILL, 2 blocks/CU = 16 waves.
__global__ __launch_bounds__(512, 4) void k_attn(
    const unsigned short* __restrict__ Q2, const unsigned short* __restrict__ Kb,
    const unsigned short* __restrict__ V2t,
    const int* __restrict__ perm, const int* __restrict__ rowc, const int* __restrict__ startPad,
    const int* __restrict__ maskI, const int* __restrict__ maskP,
    float* __restrict__ out)
{
    int bid = blockIdx.x;
    int xcd = bid & 7, local = bid >> 3;          // 0..167
    int bh = xcd * 2 + (local >= 84 ? 1 : 0);
    int it = (local >= 84) ? (local - 84) : local;
    int b = bh >> 3, h = bh & 7;
    int nTot = startPad[b * (NSEL + 1) + NSEL];
    int i0 = it * 16;
    if (i0 >= nTot) return;
    int r = rowc[b * NP + i0];
    int tiles = nTot >> 6;

    __shared__ unsigned short S[16][SSp];        // 43136 B: P (bf16)
    __shared__ float wred[8][16];
    __shared__ float wsum[8][16];
    __shared__ float pbuf[2][16][64];            // 8192 B: PV partials (j-parity halves)
    __shared__ int tilec[NPT];
    __shared__ int mrow[16];
    __shared__ int toki[16];

    int tid = threadIdx.x;
    int wave = tid >> 6, lane = tid & 63;
    int m = lane & 15, q = lane >> 4;

    const int* permB = perm + b * NP;
    const unsigned short* KbB = Kb + (size_t)bh * NP * 64;
    const unsigned short* Q2B = Q2 + (size_t)bh * NP * 64;             // + c*16*NP*64
    const unsigned short* V2B = V2t + ((size_t)r * 16 + bh) * 64 * NP; // [k][jp]
    const int* maskPB = maskP + b * NP;

    if (tid < NPT) tilec[tid] = rowc[b * NP + tid * 64];
    else if (tid >= 64 && tid < 80) {
        int rr = tid - 64;
        int tok = permB[i0 + rr];
        toki[rr] = tok;
        mrow[rr] = (tok >= 0) ? maskI[b * NN + tok] : 0;
    }
    __syncthreads();

    // ---- phase 1: scores in registers (wave stride 8 over j-tiles)
    float sarr[MAXT][4][4];
    float lmax[4] = {-INFINITY, -INFINITY, -INFINITY, -INFINITY};
    int mrow4[4];
#pragma unroll
    for (int g = 0; g < 4; g++) mrow4[g] = mrow[q * 4 + g];

#pragma unroll
    for (int tt = 0; tt < MAXT; tt++) {
        int jt = wave + tt * 8;
        bool valid = (jt < tiles);
        int jts = valid ? jt : 0;
        int c = tilec[jts];
        int jb = jts * 64;
        const unsigned short* qa = Q2B + (size_t)c * 16 * NP * 64 + (size_t)(i0 + m) * 64 + q * 8;
        bf16x8 a0 = *(const bf16x8*)qa;
        bf16x8 a1 = *(const bf16x8*)(qa + 32);
#pragma unroll
        for (int nb = 0; nb < 4; nb++) {
            int j = jb + nb * 16 + m;
            const unsigned short* kb = &KbB[(size_t)j * 64 + q * 8];
            bf16x8 b0 = *(const bf16x8*)kb;
            bf16x8 b1 = *(const bf16x8*)(kb + 32);
            f32x4 acc = {0.f, 0.f, 0.f, 0.f};
            acc = __builtin_amdgcn_mfma_f32_16x16x32_bf16(a0, b0, acc, 0, 0, 0);
            acc = __builtin_amdgcn_mfma_f32_16x16x32_bf16(a1, b1, acc, 0, 0, 0);
            int mj = maskPB[j];
#pragma unroll
            for (int g = 0; g < 4; g++) {
                float sv;
                if (!valid || mj == 2)   sv = -INFINITY;      // padding / no tile
                else if (mrow4[g] && mj) sv = acc[g] * 0.125f;
                else                     sv = -1e30f;         // reference's masked value
                sarr[tt][nb][g] = sv;
                lmax[g] = fmaxf(lmax[g], sv);
            }
        }
    }
#pragma unroll
    for (int g = 0; g < 4; g++) {
        float v = lmax[g];
#pragma unroll
        for (int o = 1; o < 16; o <<= 1) v = fmaxf(v, __shfl_xor(v, o));
        lmax[g] = v;
    }
    if (m == 0) {
#pragma unroll
        for (int g = 0; g < 4; g++) wred[wave][q * 4 + g] = lmax[g];
    }
    __syncthreads();

    // ---- phase 2: exp in regs, single P write, row sums (normalization deferred)
    float mx4[4], lsum[4] = {0.f, 0.f, 0.f, 0.f};
#pragma unroll
    for (int g = 0; g < 4; g++) {
        int i = q * 4 + g;
        float v = wred[0][i];
#pragma unroll
        for (int w2 = 1; w2 < 8; w2++) v = fmaxf(v, wred[w2][i]);
        mx4[g] = v;
    }
#pragma unroll
    for (int tt = 0; tt < MAXT; tt++) {
        int jt = wave + tt * 8;
        bool valid = (jt < tiles);
        int jb = jt * 64;
#pragma unroll
        for (int nb = 0; nb < 4; nb++) {
            int j = jb + nb * 16 + m;
#pragma unroll
            for (int g = 0; g < 4; g++) {
                float p = __expf(sarr[tt][nb][g] - mx4[g]);   // -inf -> 0
                lsum[g] += p;
                if (valid) S[q * 4 + g][j] = f2bf(p);
            }
        }
    }
#pragma unroll
    for (int g = 0; g < 4; g++) {
        float v = lsum[g];
#pragma unroll
        for (int o = 1; o < 16; o <<= 1) v += __shfl_xor(v, o);
        lsum[g] = v;
    }
    if (m == 0) {
#pragma unroll
        for (int g = 0; g < 4; g++) wsum[wave][q * 4 + g] = lsum[g];
    }
    __syncthreads();

    // ---- phase 3: out = P . V2t^T ; wave (kw,p): k-subtile kw, j-parity p
    {
        int kw = wave & 3, p = wave >> 2;
        int db = kw * 16;
        f32x4 ae = {0.f, 0.f, 0.f, 0.f};
        f32x4 ao = {0.f, 0.f, 0.f, 0.f};
        for (int jt = p; jt < tiles; jt += 2) {
            int jb = jt * 64;
            bf16x8 a0 = *(const bf16x8*)&S[m][jb + q * 8];
            bf16x8 a1 = *(const bf16x8*)&S[m][jb + 32 + q * 8];
            const unsigned short* vb = V2B + (size_t)(db + m) * NP + jb + q * 8;
            bf16x8 b0 = *(const bf16x8*)vb;
            bf16x8 b1 = *(const bf16x8*)(vb + 32);
            ae = __builtin_amdgcn_mfma_f32_16x16x32_bf16(a0, b0, ae, 0, 0, 0);
            ao = __builtin_amdgcn_mfma_f32_16x16x32_bf16(a1, b1, ao, 0, 0, 0);
        }
#pragma unroll
        for (int g = 0; g < 4; g++)
            pbuf[p][q * 4 + g][db + m] = ae[g] + ao[g];
    }
    __syncthreads();

    // ---- epilogue: combine parities, normalize, store
    for (int idx = tid; idx < 16 * 64; idx += 512) {
        int i = idx >> 6, k = idx & 63;
        int tok = toki[i];
        if (tok >= 0) {
            float s = wsum[0][i] + wsum[1][i] + wsum[2][i] + wsum[3][i]
                    + wsum[4][i] + wsum[5][i] + wsum[6][i] + wsum[7][i];
            float v = pbuf[0][i][k] + pbuf[1][i][k];
            out[((size_t)b * NN + tok) * (NH * DKK) + h * DKK + k] = v / s;
        }
    }
}

// ---------------------------------------------------------------- launch
extern "C" void kernel_launch(void* const* d_in, const int* in_sizes, int n_in,
                              void* d_out, int out_size, void* d_ws, size_t ws_size,
                              hipStream_t stream)
{
    const float* qr  = (const float*)d_in[0];
    const float* kr  = (const float*)d_in[1];
    const float* vr  = (const float*)d_in[2];
    const void* bsr  = d_in[3];
    const void* mkr  = d_in[4];
    const float* lr  = (const float*)d_in[5];
    const float* w1r = (const float*)d_in[6];
    const float* a1r = (const float*)d_in[7];
    const float* w2r = (const float*)d_in[8];
    const float* a2r = (const float*)d_in[9];
    float* out = (float*)d_out;

    char* w = (char*)d_ws;
    int* maskI    = (int*)w;
    int* perm     = maskI + BQ * NN;
    int* rowc     = perm + BQ * NP;
    int* startPad = rowc + BQ * NP;
    int* maskP    = startPad + 12;
    unsigned short* W1bt = (unsigned short*)(w + 65536);
    unsigned short* W2bt = W1bt + (size_t)NCLS * NH * 4096;
    unsigned short* Qb   = (unsigned short*)(w + 2359296);
    unsigned short* Kb   = Qb + (size_t)BQ * NH * NP * 64;
    unsigned short* Vb   = Kb + (size_t)BQ * NH * NP * 64;
    unsigned short* Lt   = (unsigned short*)(w + 10616832);          // dead after k_proj
    unsigned short* Q2   = Lt;                                       // aliases Lt (stream-ordered safe)
    unsigned short* V2t  = (unsigned short*)(w + 24379392);
    unsigned short* Xc   = (unsigned short*)(w + 38141952);          // 6.3 MB -> total ~44.4 MB

    hipLaunchKernelGGL(k_setup, dim3(1), dim3(256), 0, stream,
                       bsr, mkr, maskI, perm, rowc, startPad, maskP);
    hipLaunchKernelGGL(k_prep, dim3(960 + 2 * NCLS * NH + 96), dim3(256), 0, stream,
                       lr, Lt, w1r, w2r, a1r, a2r, W1bt, W2bt, qr, kr, vr, Xc);
    hipLaunchKernelGGL(k_proj, dim3(672), dim3(256), 0, stream,
                       Xc, Lt, perm, rowc, startPad, Qb, Kb, Vb);
    hipLaunchKernelGGL(k_qv2, dim3(8 * 4 * 105), dim3(256), 0, stream,
                       Qb, Vb, W1bt, W2bt, rowc, startPad, Q2, V2t);
    hipLaunchKernelGGL(k_attn, dim3(8 * 2 * 84), dim3(512), 0, stream,
                       Q2, Kb, V2t, perm, rowc, startPad, maskI, maskP, out);
}

// Round 10
// 190.488 us; speedup vs baseline: 1.1587x; 1.0965x over previous
//
#include <hip/hip_runtime.h>
#include <hip/hip_bf16.h>
#include <math.h>

#define BQ   2      // batch
#define NN   1024   // seq len
#define DMD  512    // d_model
#define NH   8      // heads
#define DKK  64     // head dim
#define NSEL 5      // NB+1 block values (0..4)
#define NCLS 17     // block-pair classes
#define NP   1344   // padded per-batch capacity (buckets padded to 64)
#define NPT  21     // NP/64 tiles
#define MAXT 3      // max key-tiles per wave in k_attn (ceil(21/8))
#define SSp  1348   // S row stride (shorts): conflict-free (measured 75K conflicts)
#define QLS  68     // qloc row stride (shorts): same 2m+4q bank pattern as S

typedef __attribute__((ext_vector_type(8))) short bf16x8;
typedef __attribute__((ext_vector_type(8))) unsigned short u16x8;
typedef __attribute__((ext_vector_type(4))) float f32x4;

__device__ __forceinline__ int clsOf(int r, int c) { return (r == 0 || c == 0) ? 0 : ((r - 1) * 4 + c); }

__device__ __forceinline__ unsigned short f2bf(float x) {
    __hip_bfloat16 h = __float2bfloat16(x);
    return *reinterpret_cast<unsigned short*>(&h);
}

// ---------------------------------------------------------------- prep: lin cast (960) + wmix (272) + qkv cast (96) + setup (1)
__global__ __launch_bounds__(256) void k_prep(
    const float* __restrict__ lr, unsigned short* __restrict__ Lt,
    const float* __restrict__ W1, const float* __restrict__ W2,
    const float* __restrict__ al1, const float* __restrict__ al2,
    unsigned short* __restrict__ W1bt, unsigned short* __restrict__ W2bt,
    const float* __restrict__ qr, const float* __restrict__ kr, const float* __restrict__ vr,
    unsigned short* __restrict__ Xc,
    const void* __restrict__ b_seq_r, const void* __restrict__ mask_r,
    int* __restrict__ maskI, int* __restrict__ perm, int* __restrict__ rowc,
    int* __restrict__ startPad, int* __restrict__ maskP)
{
    __shared__ float Tf[64][68];
    __shared__ int det[5];
    __shared__ int cnts[BQ][NSEL];
    __shared__ int offs[BQ][NSEL];
    __shared__ int sstart[BQ][NSEL + 1];
    int bx = blockIdx.x;
    int tid = threadIdx.x;
    if (bx < 960) {
        // cast+transpose lin[ts][k][n] -> Lt[ts][n][k] bf16
        int ts = bx >> 6, rem = bx & 63;
        int kt = rem >> 3, nt = rem & 7;
        const float* src = lr + (size_t)ts * DMD * 512;
        unsigned short* dst = Lt + (size_t)ts * DMD * 512;
        int r = tid >> 2, c4 = tid & 3;
#pragma unroll
        for (int i = 0; i < 4; i++) {
            float4 v = *(const float4*)&src[(size_t)(kt * 64 + r) * 512 + nt * 64 + c4 * 16 + i * 4];
            *(float4*)&Tf[r][c4 * 16 + i * 4] = v;
        }
        __syncthreads();
        unsigned short tmp[16];
#pragma unroll
        for (int i = 0; i < 16; i++) tmp[i] = f2bf(Tf[c4 * 16 + i][r]);
        u16x8 o0, o1;
#pragma unroll
        for (int i = 0; i < 8; i++) { o0[i] = tmp[i]; o1[i] = tmp[8 + i]; }
        unsigned short* dp = &dst[(size_t)(nt * 64 + r) * 512 + kt * 64 + c4 * 16];
        *(u16x8*)&dp[0] = o0;
        *(u16x8*)&dp[8] = o1;
    } else if (bx < 960 + 2 * NCLS * NH) {
        int bid = bx - 960;
        int w = bid / (NCLS * NH);
        int rem = bid % (NCLS * NH);
        int c = rem / NH, h = rem % NH;
        const float* W = w ? W2 : W1;
        const float* a = w ? al2 : al1;
        unsigned short* outp = (w ? W2bt : W1bt) + (((size_t)c * NH + h) << 12);
        float vals[4], mx = -1e30f;
#pragma unroll
        for (int bb = 0; bb < 4; bb++) { vals[bb] = a[(c * 4 + bb) * NH + h]; mx = fmaxf(mx, vals[bb]); }
        float ssum = 0.f;
#pragma unroll
        for (int bb = 0; bb < 4; bb++) { vals[bb] = __expf(vals[bb] - mx); ssum += vals[bb]; }
        float inv = 1.0f / ssum;
        float s0 = vals[0] * inv, s1 = vals[1] * inv, s2 = vals[2] * inv, s3 = vals[3] * inv;
        const float* p0 = W + (size_t)(0 * NH + h) * 4096;
        const float* p1 = W + (size_t)(1 * NH + h) * 4096;
        const float* p2 = W + (size_t)(2 * NH + h) * 4096;
        const float* p3 = W + (size_t)(3 * NH + h) * 4096;
        for (int e = tid; e < 4096; e += 256) {
            float v = s0 * p0[e] + s1 * p1[e] + s2 * p2[e] + s3 * p3[e];
            int mm = e >> 6, nn = e & 63;
            outp[nn * 64 + mm] = f2bf(v);     // transposed store
        }
    } else if (bx < 960 + 2 * NCLS * NH + 96) {
        // cast q/k/v -> Xc bf16 [t][b][n][512]
        int bid = bx - (960 + 2 * NCLS * NH);   // 0..95
        int t = bid / 32, rem = bid % 32;
        int b = rem / 16, rg = rem % 16;
        int row = tid >> 2, part = tid & 3;
        const float* X = (t == 0) ? qr : ((t == 1) ? kr : vr);
        const float* src = X + ((size_t)b * NN + rg * 64 + row) * DMD + part * 128;
        unsigned short* dst = Xc + (((size_t)t * BQ + b) * NN + rg * 64 + row) * DMD + part * 128;
#pragma unroll
        for (int i = 0; i < 128; i += 8) {
            float4 v0 = *(const float4*)&src[i];
            float4 v1 = *(const float4*)&src[i + 4];
            u16x8 o;
            o[0] = f2bf(v0.x); o[1] = f2bf(v0.y); o[2] = f2bf(v0.z); o[3] = f2bf(v0.w);
            o[4] = f2bf(v1.x); o[5] = f2bf(v1.y); o[6] = f2bf(v1.z); o[7] = f2bf(v1.w);
            *(u16x8*)&dst[i] = o;
        }
    } else {
        // ---- setup (single block): dtype detect, bucketize, perm, masks
        if (tid < 5) det[tid] = 0;
        if (tid < BQ * NSEL) { cnts[tid / NSEL][tid % NSEL] = 0; offs[tid / NSEL][tid % NSEL] = 0; }
        __syncthreads();
        const int* b32 = (const int*)b_seq_r;
        const unsigned char* mb = (const unsigned char*)mask_r;
        const int* m32 = (const int*)mask_r;
        if (tid < 64) {
            if (b32[2 * tid + 1] != 0) atomicOr(&det[0], 1);
            if (b32[2 * tid] != 0)     atomicOr(&det[1], 1);
            if (m32[2 * tid + 1] != 0) atomicOr(&det[3], 1);
            if (m32[2 * tid] != 0)     atomicOr(&det[4], 1);
        }
        if ((tid & 3) != 0 && mb[tid] != 0) atomicOr(&det[2], 1);
        __syncthreads();
        int bsI64 = (det[0] == 0 && det[1] != 0);
        int mk = det[2] ? 1 : ((det[3] == 0 && det[4] != 0) ? 2 : 0);

        for (int g = tid; g < BQ * NN; g += 256) {
            int m = (mk == 1) ? (mb[g] != 0) : ((mk == 2) ? (m32[2 * g] != 0) : (m32[g] != 0));
            maskI[g] = m;
            int bs = bsI64 ? b32[2 * g] : b32[g];
            bs = bs < 0 ? 0 : (bs > 4 ? 4 : bs);
            atomicAdd(&cnts[g / NN][bs], 1);
        }
        __syncthreads();
        if (tid == 0) {
            for (int b = 0; b < BQ; b++) {
                int acc = 0;
                for (int c = 0; c < NSEL; c++) {
                    sstart[b][c] = acc;
                    acc += ((cnts[b][c] + 63) / 64) * 64;
                }
                sstart[b][NSEL] = acc;
                for (int c = 0; c <= NSEL; c++) startPad[b * (NSEL + 1) + c] = sstart[b][c];
            }
        }
        __syncthreads();
        for (int g = tid; g < BQ * NP; g += 256) {
            perm[g] = -1;
            int b = g / NP, sslot = g % NP;
            int c = 0;
            for (int cc = 1; cc < NSEL; cc++) if (sslot >= sstart[b][cc]) c = cc;
            rowc[g] = c;
        }
        __syncthreads();
        for (int g = tid; g < BQ * NN; g += 256) {
            int b = g / NN, n = g % NN;
            int bs = bsI64 ? b32[2 * g] : b32[g];
            bs = bs < 0 ? 0 : (bs > 4 ? 4 : bs);
            int pos = sstart[b][bs] + atomicAdd(&offs[b][bs], 1);
            perm[b * NP + pos] = n;
        }
        __syncthreads();
        for (int g = tid; g < BQ * NP; g += 256) {
            int tok = perm[g];
            maskP[g] = (tok < 0) ? 2 : maskI[(g / NP) * NN + tok];
        }
    }
}

// ---------------------------------------------------------------- bucketed QKV projection, MFMA bf16 (XCD-grouped, pipelined)
__global__ __launch_bounds__(256) void k_proj(
    const unsigned short* __restrict__ Xc,
    const unsigned short* __restrict__ Lt,
    const int* __restrict__ perm, const int* __restrict__ rowc, const int* __restrict__ startPad,
    unsigned short* __restrict__ Qb, unsigned short* __restrict__ Kb, unsigned short* __restrict__ Vb)
{
    int bid = blockIdx.x;
    int xcd = bid & 7, local = bid >> 3;          // 0..83
    int g;
    if (local < 42) g = xcd;
    else { if (xcd >= 4) return; g = xcd + 8; }
    int idx = local % 42;
    int t = g >> 2, qtr = g & 3;
    int ti = idx >> 1, b = idx & 1;

    int nTot = startPad[b * (NSEL + 1) + NSEL];
    if (ti * 64 >= nTot) return;
    int sel = rowc[b * NP + ti * 64];
    const unsigned short* XcT = Xc + ((size_t)t * BQ + b) * NN * DMD;
    const unsigned short* L = Lt + (size_t)(t * NSEL + sel) * DMD * 512;   // [n][k] bf16

    __shared__ __align__(16) unsigned short Xb[64][72];
    __shared__ __align__(16) unsigned short Lb[128][72];
    __shared__ int toks[64];

    int tid = threadIdx.x;
    int wave = tid >> 6, lane = tid & 63;
    int m = lane & 15, q = lane >> 4;
    if (tid < 64) toks[tid] = perm[b * NP + ti * 64 + tid];
    __syncthreads();

    int xr = tid >> 2, xc0 = (tid & 3) * 16;
    int xtok = toks[xr];
    const unsigned short* xbase = (xtok >= 0) ? &XcT[(size_t)xtok * DMD] : (const unsigned short*)0;
    int ln = tid >> 1, lhf = tid & 1;
    const unsigned short* lbase = &L[(size_t)(qtr * 128 + ln) * 512 + lhf * 32];

    u16x8 rx0 = {0, 0, 0, 0, 0, 0, 0, 0}, rx1 = {0, 0, 0, 0, 0, 0, 0, 0};
    u16x8 rl0, rl1, rl2, rl3;
    if (xbase) { rx0 = *(const u16x8*)&xbase[xc0]; rx1 = *(const u16x8*)&xbase[xc0 + 8]; }
    rl0 = *(const u16x8*)&lbase[0];  rl1 = *(const u16x8*)&lbase[8];
    rl2 = *(const u16x8*)&lbase[16]; rl3 = *(const u16x8*)&lbase[24];

    f32x4 acc[4][2];
#pragma unroll
    for (int mt = 0; mt < 4; mt++) { acc[mt][0] = {0, 0, 0, 0}; acc[mt][1] = {0, 0, 0, 0}; }

    for (int kb = 0; kb < DMD; kb += 64) {
        *(u16x8*)&Xb[xr][xc0] = rx0;
        *(u16x8*)&Xb[xr][xc0 + 8] = rx1;
        *(u16x8*)&Lb[ln][lhf * 32 + 0]  = rl0;
        *(u16x8*)&Lb[ln][lhf * 32 + 8]  = rl1;
        *(u16x8*)&Lb[ln][lhf * 32 + 16] = rl2;
        *(u16x8*)&Lb[ln][lhf * 32 + 24] = rl3;
        __syncthreads();
        if (kb + 64 < DMD) {   // prefetch next slab: overlaps the MFMA section below
            int nk = kb + 64;
            if (xbase) { rx0 = *(const u16x8*)&xbase[nk + xc0]; rx1 = *(const u16x8*)&xbase[nk + xc0 + 8]; }
            rl0 = *(const u16x8*)&lbase[nk];      rl1 = *(const u16x8*)&lbase[nk + 8];
            rl2 = *(const u16x8*)&lbase[nk + 16]; rl3 = *(const u16x8*)&lbase[nk + 24];
        }
#pragma unroll
        for (int kc = 0; kc < 64; kc += 32) {
            bf16x8 bf0 = *(const bf16x8*)&Lb[wave * 32 + m][kc + q * 8];
            bf16x8 bf1 = *(const bf16x8*)&Lb[wave * 32 + 16 + m][kc + q * 8];
#pragma unroll
            for (int mt = 0; mt < 4; mt++) {
                bf16x8 a = *(const bf16x8*)&Xb[mt * 16 + m][kc + q * 8];
                acc[mt][0] = __builtin_amdgcn_mfma_f32_16x16x32_bf16(a, bf0, acc[mt][0], 0, 0, 0);
                acc[mt][1] = __builtin_amdgcn_mfma_f32_16x16x32_bf16(a, bf1, acc[mt][1], 0, 0, 0);
            }
        }
        __syncthreads();
    }

    unsigned short* O = (t == 0) ? Qb : ((t == 1) ? Kb : Vb);
#pragma unroll
    for (int mt = 0; mt < 4; mt++)
#pragma unroll
        for (int nt = 0; nt < 2; nt++)
#pragma unroll
            for (int gg = 0; gg < 4; gg++) {
                int i = mt * 16 + q * 4 + gg;
                int hk = qtr * 128 + wave * 32 + nt * 16 + m;
                int h = hk >> 6, k0 = hk & 63;
                O[(((size_t)b * NH + h) * NP + ti * 64 + i) * 64 + k0] = f2bf(acc[mt][nt][gg]);
            }
}

// ---------------------------------------------------------------- V2t precompute, MFMA (XCD-swizzled)
// V2t[r][bh][k][jp] = sum_d W2bt[cls(r,c(jp))][h][k][d] * Vb[jp][d]
__global__ __launch_bounds__(256) void k_qv2(
    const unsigned short* __restrict__ Vb, const unsigned short* __restrict__ W2bt,
    const int* __restrict__ rowc, const int* __restrict__ startPad,
    unsigned short* __restrict__ V2t)
{
    // 1680 blocks = 8 XCDs x 2 bh x 105 (cv,ti)
    int bid = blockIdx.x;
    int xcd = bid & 7, local = bid >> 3;          // 0..209
    int bh = xcd * 2 + local / 105;
    int rem = local % 105;
    int cv = rem / 21, ti = rem % 21;
    int b = bh >> 3, h = bh & 7;
    int nTot = startPad[b * (NSEL + 1) + NSEL];
    if (ti * 64 >= nTot) return;
    int tb = rowc[b * NP + ti * 64];
    int tid = threadIdx.x;
    int wave = tid >> 6, lane = tid & 63;
    int m = lane & 15, q = lane >> 4;

    int cls = clsOf(cv, tb);
    const unsigned short* A = W2bt + (((size_t)cls * NH + h) << 12);
    const unsigned short* B = Vb + ((size_t)bh * NP + ti * 64) * 64;
    unsigned short* C = V2t + ((size_t)cv * 16 + bh) * 64 * NP + ti * 64;

    const unsigned short* bp = B + (size_t)(wave * 16 + m) * 64 + q * 8;
    bf16x8 b0 = *(const bf16x8*)bp;
    bf16x8 b1 = *(const bf16x8*)(bp + 32);
#pragma unroll
    for (int mb = 0; mb < 4; mb++) {
        const unsigned short* ap = A + (size_t)(mb * 16 + m) * 64 + q * 8;
        bf16x8 a0 = *(const bf16x8*)ap;
        bf16x8 a1 = *(const bf16x8*)(ap + 32);
        f32x4 acc = {0.f, 0.f, 0.f, 0.f};
        acc = __builtin_amdgcn_mfma_f32_16x16x32_bf16(a0, b0, acc, 0, 0, 0);
        acc = __builtin_amdgcn_mfma_f32_16x16x32_bf16(a1, b1, acc, 0, 0, 0);
#pragma unroll
        for (int g = 0; g < 4; g++)
            C[(size_t)(mb * 16 + q * 4 + g) * NP + wave * 16 + m] = f2bf(acc[g]);
    }
}

// ---------------------------------------------------------------- fused attention: 512 threads, XCD-swizzled, in-kernel Q2
__global__ __launch_bounds__(512, 4) void k_attn(
    const unsigned short* __restrict__ Qb, const unsigned short* __restrict__ Kb,
    const unsigned short* __restrict__ V2t, const unsigned short* __restrict__ W1bt,
    const int* __restrict__ perm, const int* __restrict__ rowc, const int* __restrict__ startPad,
    const int* __restrict__ maskI, const int* __restrict__ maskP,
    float* __restrict__ out)
{
    int bid = blockIdx.x;
    int xcd = bid & 7, local = bid >> 3;          // 0..167
    int bh = xcd * 2 + (local >= 84 ? 1 : 0);
    int it = (local >= 84) ? (local - 84) : local;
    int b = bh >> 3, h = bh & 7;
    int nTot = startPad[b * (NSEL + 1) + NSEL];
    int i0 = it * 16;
    if (i0 >= nTot) return;
    int r = rowc[b * NP + i0];
    int tiles = nTot >> 6;

    __shared__ unsigned short S[16][SSp];                        // 43136 B
    __shared__ __align__(16) unsigned short qloc[NSEL][16][QLS]; // 10880 B
    __shared__ float wred[8][16];
    __shared__ float wsum[8][16];
    __shared__ float pbuf[2][16][64];                            // 8192 B
    __shared__ int tilec[NPT];
    __shared__ int mrow[16];
    __shared__ int toki[16];

    int tid = threadIdx.x;
    int wave = tid >> 6, lane = tid & 63;
    int m = lane & 15, q = lane >> 4;

    const int* permB = perm + b * NP;
    const unsigned short* QbB = Qb + (size_t)bh * NP * 64;
    const unsigned short* KbB = Kb + (size_t)bh * NP * 64;
    const unsigned short* V2B = V2t + ((size_t)r * 16 + bh) * 64 * NP; // [k][jp]
    const int* maskPB = maskP + b * NP;

    if (tid < NPT) tilec[tid] = rowc[b * NP + tid * 64];
    else if (tid >= 64 && tid < 80) {
        int rr = tid - 64;
        int tok = permB[i0 + rr];
        toki[rr] = tok;
        mrow[rr] = (tok >= 0) ? maskI[b * NN + tok] : 0;
    }

    // ---- phase 0b: qloc[c][i][n] = Q . W1m[cls(r,c)]; 8 waves = {c-half} x {n-subtile}
    {
        const unsigned short* qa = &QbB[(size_t)(i0 + m) * 64 + q * 8];
        bf16x8 a0 = *(const bf16x8*)qa;
        bf16x8 a1 = *(const bf16x8*)(qa + 32);
        int sub = wave & 3;
        int c0 = (wave >> 2) ? 3 : 0;
        int c1 = (wave >> 2) ? 5 : 3;
        for (int c = c0; c < c1; c++) {
            int cls = clsOf(r, c);
            const unsigned short* wb = W1bt + (((size_t)cls * NH + h) << 12)
                                     + (size_t)(sub * 16 + m) * 64 + q * 8;
            bf16x8 b0 = *(const bf16x8*)wb;
            bf16x8 b1 = *(const bf16x8*)(wb + 32);
            f32x4 acc = {0.f, 0.f, 0.f, 0.f};
            acc = __builtin_amdgcn_mfma_f32_16x16x32_bf16(a0, b0, acc, 0, 0, 0);
            acc = __builtin_amdgcn_mfma_f32_16x16x32_bf16(a1, b1, acc, 0, 0, 0);
#pragma unroll
            for (int g = 0; g < 4; g++)
                qloc[c][q * 4 + g][sub * 16 + m] = f2bf(acc[g]);
        }
    }
    __syncthreads();

    // ---- phase 1: scores in registers (wave stride 8 over j-tiles)
    float sarr[MAXT][4][4];
    float lmax[4] = {-INFINITY, -INFINITY, -INFINITY, -INFINITY};
    int mrow4[4];
#pragma unroll
    for (int g = 0; g < 4; g++) mrow4[g] = mrow[q * 4 + g];

#pragma unroll
    for (int tt = 0; tt < MAXT; tt++) {
        int jt = wave + tt * 8;
        bool valid = (jt < tiles);
        int jts = valid ? jt : 0;
        int c = tilec[jts];
        int jb = jts * 64;
        const unsigned short* qa = &qloc[c][m][q * 8];
        bf16x8 a0 = *(const bf16x8*)qa;
        bf16x8 a1 = *(const bf16x8*)(qa + 32);
#pragma unroll
        for (int nb = 0; nb < 4; nb++) {
            int j = jb + nb * 16 + m;
            const unsigned short* kb = &KbB[(size_t)j * 64 + q * 8];
            bf16x8 b0 = *(const bf16x8*)kb;
            bf16x8 b1 = *(const bf16x8*)(kb + 32);
            f32x4 acc = {0.f, 0.f, 0.f, 0.f};
            acc = __builtin_amdgcn_mfma_f32_16x16x32_bf16(a0, b0, acc, 0, 0, 0);
            acc = __builtin_amdgcn_mfma_f32_16x16x32_bf16(a1, b1, acc, 0, 0, 0);
            int mj = maskPB[j];
#pragma unroll
            for (int g = 0; g < 4; g++) {
                float sv;
                if (!valid || mj == 2)   sv = -INFINITY;      // padding / no tile
                else if (mrow4[g] && mj) sv = acc[g] * 0.125f;
                else                     sv = -1e30f;         // reference's masked value
                sarr[tt][nb][g] = sv;
                lmax[g] = fmaxf(lmax[g], sv);
            }
        }
    }
#pragma unroll
    for (int g = 0; g < 4; g++) {
        float v = lmax[g];
#pragma unroll
        for (int o = 1; o < 16; o <<= 1) v = fmaxf(v, __shfl_xor(v, o));
        lmax[g] = v;
    }
    if (m == 0) {
#pragma unroll
        for (int g = 0; g < 4; g++) wred[wave][q * 4 + g] = lmax[g];
    }
    __syncthreads();

    // ---- phase 2: exp in regs, single P write, row sums (normalization deferred)
    float mx4[4], lsum[4] = {0.f, 0.f, 0.f, 0.f};
#pragma unroll
    for (int g = 0; g < 4; g++) {
        int i = q * 4 + g;
        float v = wred[0][i];
#pragma unroll
        for (int w2 = 1; w2 < 8; w2++) v = fmaxf(v, wred[w2][i]);
        mx4[g] = v;
    }
#pragma unroll
    for (int tt = 0; tt < MAXT; tt++) {
        int jt = wave + tt * 8;
        bool valid = (jt < tiles);
        int jb = jt * 64;
#pragma unroll
        for (int nb = 0; nb < 4; nb++) {
            int j = jb + nb * 16 + m;
#pragma unroll
            for (int g = 0; g < 4; g++) {
                float p = __expf(sarr[tt][nb][g] - mx4[g]);   // -inf -> 0
                lsum[g] += p;
                if (valid) S[q * 4 + g][j] = f2bf(p);
            }
        }
    }
#pragma unroll
    for (int g = 0; g < 4; g++) {
        float v = lsum[g];
#pragma unroll
        for (int o = 1; o < 16; o <<= 1) v += __shfl_xor(v, o);
        lsum[g] = v;
    }
    if (m == 0) {
#pragma unroll
        for (int g = 0; g < 4; g++) wsum[wave][q * 4 + g] = lsum[g];
    }
    __syncthreads();

    // ---- phase 3: out = P . V2t^T ; wave (kw,p): k-subtile kw, j-parity p
    {
        int kw = wave & 3, p = wave >> 2;
        int db = kw * 16;
        f32x4 ae = {0.f, 0.f, 0.f, 0.f};
        f32x4 ao = {0.f, 0.f, 0.f, 0.f};
        for (int jt = p; jt < tiles; jt += 2) {
            int jb = jt * 64;
            bf16x8 a0 = *(const bf16x8*)&S[m][jb + q * 8];
            bf16x8 a1 = *(const bf16x8*)&S[m][jb + 32 + q * 8];
            const unsigned short* vb = V2B + (size_t)(db + m) * NP + jb + q * 8;
            bf16x8 b0 = *(const bf16x8*)vb;
            bf16x8 b1 = *(const bf16x8*)(vb + 32);
            ae = __builtin_amdgcn_mfma_f32_16x16x32_bf16(a0, b0, ae, 0, 0, 0);
            ao = __builtin_amdgcn_mfma_f32_16x16x32_bf16(a1, b1, ao, 0, 0, 0);
        }
#pragma unroll
        for (int g = 0; g < 4; g++)
            pbuf[p][q * 4 + g][db + m] = ae[g] + ao[g];
    }
    __syncthreads();

    // ---- epilogue: combine parities, normalize, store
    for (int idx = tid; idx < 16 * 64; idx += 512) {
        int i = idx >> 6, k = idx & 63;
        int tok = toki[i];
        if (tok >= 0) {
            float s = wsum[0][i] + wsum[1][i] + wsum[2][i] + wsum[3][i]
                    + wsum[4][i] + wsum[5][i] + wsum[6][i] + wsum[7][i];
            float v = pbuf[0][i][k] + pbuf[1][i][k];
            out[((size_t)b * NN + tok) * (NH * DKK) + h * DKK + k] = v / s;
        }
    }
}

// ---------------------------------------------------------------- launch
extern "C" void kernel_launch(void* const* d_in, const int* in_sizes, int n_in,
                              void* d_out, int out_size, void* d_ws, size_t ws_size,
                              hipStream_t stream)
{
    const float* qr  = (const float*)d_in[0];
    const float* kr  = (const float*)d_in[1];
    const float* vr  = (const float*)d_in[2];
    const void* bsr  = d_in[3];
    const void* mkr  = d_in[4];
    const float* lr  = (const float*)d_in[5];
    const float* w1r = (const float*)d_in[6];
    const float* a1r = (const float*)d_in[7];
    const float* w2r = (const float*)d_in[8];
    const float* a2r = (const float*)d_in[9];
    float* out = (float*)d_out;

    char* w = (char*)d_ws;
    int* maskI    = (int*)w;
    int* perm     = maskI + BQ * NN;
    int* rowc     = perm + BQ * NP;
    int* startPad = rowc + BQ * NP;
    int* maskP    = startPad + 12;
    unsigned short* W1bt = (unsigned short*)(w + 65536);
    unsigned short* W2bt = W1bt + (size_t)NCLS * NH * 4096;
    unsigned short* Qb   = (unsigned short*)(w + 2359296);
    unsigned short* Kb   = Qb + (size_t)BQ * NH * NP * 64;
    unsigned short* Vb   = Kb + (size_t)BQ * NH * NP * 64;
    unsigned short* Lt   = (unsigned short*)(w + 10616832);
    unsigned short* V2t  = (unsigned short*)(w + 24379392);
    unsigned short* Xc   = (unsigned short*)(w + 38141952);          // total ~44.4 MB

    hipLaunchKernelGGL(k_prep, dim3(960 + 2 * NCLS * NH + 96 + 1), dim3(256), 0, stream,
                       lr, Lt, w1r, w2r, a1r, a2r, W1bt, W2bt, qr, kr, vr, Xc,
                       bsr, mkr, maskI, perm, rowc, startPad, maskP);
    hipLaunchKernelGGL(k_proj, dim3(672), dim3(256), 0, stream,
                       Xc, Lt, perm, rowc, startPad, Qb, Kb, Vb);
    hipLaunchKernelGGL(k_qv2, dim3(1680), dim3(256), 0, stream,
                       Vb, W2bt, rowc, startPad, V2t);
    hipLaunchKernelGGL(k_attn, dim3(8 * 2 * 84), dim3(512), 0, stream,
                       Qb, Kb, V2t, W1bt, perm, rowc, startPad, maskI, maskP, out);
}

// Round 11
// 188.236 us; speedup vs baseline: 1.1725x; 1.0120x over previous
//
#include <hip/hip_runtime.h>
#include <hip/hip_bf16.h>
#include <math.h>

#define BQ   2      // batch
#define NN   1024   // seq len
#define DMD  512    // d_model
#define NH   8      // heads
#define DKK  64     // head dim
#define NSEL 5      // NB+1 block values (0..4)
#define NCLS 17     // block-pair classes
#define NP   1344   // padded per-batch capacity (buckets padded to 64)
#define NPT  21     // NP/64 tiles
#define MAXT 3      // max key-tiles per wave in k_attn (ceil(21/8))
#define SSp  1348   // S row stride (shorts): conflict-free
#define QLS  68     // qloc row stride (shorts)

typedef __attribute__((ext_vector_type(8))) short bf16x8;
typedef __attribute__((ext_vector_type(8))) unsigned short u16x8;
typedef __attribute__((ext_vector_type(4))) float f32x4;

__device__ __forceinline__ int clsOf(int r, int c) { return (r == 0 || c == 0) ? 0 : ((r - 1) * 4 + c); }

__device__ __forceinline__ unsigned short f2bf(float x) {
    __hip_bfloat16 h = __float2bfloat16(x);
    return *reinterpret_cast<unsigned short*>(&h);
}

// ---------------------------------------------------------------- prep: lin cast (960) + wmix (272) + qkv cast (96) + setup (1)
__global__ __launch_bounds__(256) void k_prep(
    const float* __restrict__ lr, unsigned short* __restrict__ Lt,
    const float* __restrict__ W1, const float* __restrict__ W2,
    const float* __restrict__ al1, const float* __restrict__ al2,
    unsigned short* __restrict__ W1bt, unsigned short* __restrict__ W2bt,
    const float* __restrict__ qr, const float* __restrict__ kr, const float* __restrict__ vr,
    unsigned short* __restrict__ Xc,
    const void* __restrict__ b_seq_r, const void* __restrict__ mask_r,
    int* __restrict__ maskI, int* __restrict__ perm, int* __restrict__ rowc,
    int* __restrict__ startPad, int* __restrict__ maskP)
{
    __shared__ float Tf[64][68];
    __shared__ int det[5];
    __shared__ int cnts[BQ][NSEL];
    __shared__ int offs[BQ][NSEL];
    __shared__ int sstart[BQ][NSEL + 1];
    int bx = blockIdx.x;
    int tid = threadIdx.x;
    if (bx < 960) {
        // cast+transpose lin[ts][k][n] -> Lt[ts][n][k] bf16
        int ts = bx >> 6, rem = bx & 63;
        int kt = rem >> 3, nt = rem & 7;
        const float* src = lr + (size_t)ts * DMD * 512;
        unsigned short* dst = Lt + (size_t)ts * DMD * 512;
        int r = tid >> 2, c4 = tid & 3;
#pragma unroll
        for (int i = 0; i < 4; i++) {
            float4 v = *(const float4*)&src[(size_t)(kt * 64 + r) * 512 + nt * 64 + c4 * 16 + i * 4];
            *(float4*)&Tf[r][c4 * 16 + i * 4] = v;
        }
        __syncthreads();
        unsigned short tmp[16];
#pragma unroll
        for (int i = 0; i < 16; i++) tmp[i] = f2bf(Tf[c4 * 16 + i][r]);
        u16x8 o0, o1;
#pragma unroll
        for (int i = 0; i < 8; i++) { o0[i] = tmp[i]; o1[i] = tmp[8 + i]; }
        unsigned short* dp = &dst[(size_t)(nt * 64 + r) * 512 + kt * 64 + c4 * 16];
        *(u16x8*)&dp[0] = o0;
        *(u16x8*)&dp[8] = o1;
    } else if (bx < 960 + 2 * NCLS * NH) {
        int bid = bx - 960;
        int w = bid / (NCLS * NH);
        int rem = bid % (NCLS * NH);
        int c = rem / NH, h = rem % NH;
        const float* W = w ? W2 : W1;
        const float* a = w ? al2 : al1;
        unsigned short* outp = (w ? W2bt : W1bt) + (((size_t)c * NH + h) << 12);
        float vals[4], mx = -1e30f;
#pragma unroll
        for (int bb = 0; bb < 4; bb++) { vals[bb] = a[(c * 4 + bb) * NH + h]; mx = fmaxf(mx, vals[bb]); }
        float ssum = 0.f;
#pragma unroll
        for (int bb = 0; bb < 4; bb++) { vals[bb] = __expf(vals[bb] - mx); ssum += vals[bb]; }
        float inv = 1.0f / ssum;
        float s0 = vals[0] * inv, s1 = vals[1] * inv, s2 = vals[2] * inv, s3 = vals[3] * inv;
        const float* p0 = W + (size_t)(0 * NH + h) * 4096;
        const float* p1 = W + (size_t)(1 * NH + h) * 4096;
        const float* p2 = W + (size_t)(2 * NH + h) * 4096;
        const float* p3 = W + (size_t)(3 * NH + h) * 4096;
        for (int e = tid; e < 4096; e += 256) {
            float v = s0 * p0[e] + s1 * p1[e] + s2 * p2[e] + s3 * p3[e];
            int mm = e >> 6, nn = e & 63;
            outp[nn * 64 + mm] = f2bf(v);     // transposed store
        }
    } else if (bx < 960 + 2 * NCLS * NH + 96) {
        // cast q/k/v -> Xc bf16 [t][b][n][512]
        int bid = bx - (960 + 2 * NCLS * NH);   // 0..95
        int t = bid / 32, rem = bid % 32;
        int b = rem / 16, rg = rem % 16;
        int row = tid >> 2, part = tid & 3;
        const float* X = (t == 0) ? qr : ((t == 1) ? kr : vr);
        const float* src = X + ((size_t)b * NN + rg * 64 + row) * DMD + part * 128;
        unsigned short* dst = Xc + (((size_t)t * BQ + b) * NN + rg * 64 + row) * DMD + part * 128;
#pragma unroll
        for (int i = 0; i < 128; i += 8) {
            float4 v0 = *(const float4*)&src[i];
            float4 v1 = *(const float4*)&src[i + 4];
            u16x8 o;
            o[0] = f2bf(v0.x); o[1] = f2bf(v0.y); o[2] = f2bf(v0.z); o[3] = f2bf(v0.w);
            o[4] = f2bf(v1.x); o[5] = f2bf(v1.y); o[6] = f2bf(v1.z); o[7] = f2bf(v1.w);
            *(u16x8*)&dst[i] = o;
        }
    } else {
        // ---- setup (single block): dtype detect, bucketize, perm, masks
        if (tid < 5) det[tid] = 0;
        if (tid < BQ * NSEL) { cnts[tid / NSEL][tid % NSEL] = 0; offs[tid / NSEL][tid % NSEL] = 0; }
        __syncthreads();
        const int* b32 = (const int*)b_seq_r;
        const unsigned char* mb = (const unsigned char*)mask_r;
        const int* m32 = (const int*)mask_r;
        if (tid < 64) {
            if (b32[2 * tid + 1] != 0) atomicOr(&det[0], 1);
            if (b32[2 * tid] != 0)     atomicOr(&det[1], 1);
            if (m32[2 * tid + 1] != 0) atomicOr(&det[3], 1);
            if (m32[2 * tid] != 0)     atomicOr(&det[4], 1);
        }
        if ((tid & 3) != 0 && mb[tid] != 0) atomicOr(&det[2], 1);
        __syncthreads();
        int bsI64 = (det[0] == 0 && det[1] != 0);
        int mk = det[2] ? 1 : ((det[3] == 0 && det[4] != 0) ? 2 : 0);

        for (int g = tid; g < BQ * NN; g += 256) {
            int m = (mk == 1) ? (mb[g] != 0) : ((mk == 2) ? (m32[2 * g] != 0) : (m32[g] != 0));
            maskI[g] = m;
            int bs = bsI64 ? b32[2 * g] : b32[g];
            bs = bs < 0 ? 0 : (bs > 4 ? 4 : bs);
            atomicAdd(&cnts[g / NN][bs], 1);
        }
        __syncthreads();
        if (tid == 0) {
            for (int b = 0; b < BQ; b++) {
                int acc = 0;
                for (int c = 0; c < NSEL; c++) {
                    sstart[b][c] = acc;
                    acc += ((cnts[b][c] + 63) / 64) * 64;
                }
                sstart[b][NSEL] = acc;
                for (int c = 0; c <= NSEL; c++) startPad[b * (NSEL + 1) + c] = sstart[b][c];
            }
        }
        __syncthreads();
        for (int g = tid; g < BQ * NP; g += 256) {
            perm[g] = -1;
            int b = g / NP, sslot = g % NP;
            int c = 0;
            for (int cc = 1; cc < NSEL; cc++) if (sslot >= sstart[b][cc]) c = cc;
            rowc[g] = c;
        }
        __syncthreads();
        for (int g = tid; g < BQ * NN; g += 256) {
            int b = g / NN, n = g % NN;
            int bs = bsI64 ? b32[2 * g] : b32[g];
            bs = bs < 0 ? 0 : (bs > 4 ? 4 : bs);
            int pos = sstart[b][bs] + atomicAdd(&offs[b][bs], 1);
            perm[b * NP + pos] = n;
        }
        __syncthreads();
        for (int g = tid; g < BQ * NP; g += 256) {
            int tok = perm[g];
            maskP[g] = (tok < 0) ? 2 : maskI[(g / NP) * NN + tok];
        }
    }
}

// ---------------------------------------------------------------- QKV projection + fused V2t, MFMA bf16
// 504 blocks = 8 XCDs x 63. Each XCD: 42 blocks of its t<2 group + 21 t=2 blocks.
// t<2 -> Qb/Kb[b][h][ip][64]; t=2 -> V2t[r][bh][k][jp] directly (all 5 r, 2 heads).
__global__ __launch_bounds__(256) void k_proj(
    const unsigned short* __restrict__ Xc,
    const unsigned short* __restrict__ Lt,
    const unsigned short* __restrict__ W2bt,
    const int* __restrict__ perm, const int* __restrict__ rowc, const int* __restrict__ startPad,
    unsigned short* __restrict__ Qb, unsigned short* __restrict__ Kb,
    unsigned short* __restrict__ V2t)
{
    int bid = blockIdx.x;
    int xcd = bid & 7, local = bid >> 3;          // 0..62
    int t, qtr, ti, b;
    if (local < 42) {
        int g = xcd;                               // groups 0..7 = (t,qtr) for t<2
        t = g >> 2; qtr = g & 3;
        ti = local >> 1; b = local & 1;
    } else {
        t = 2; qtr = xcd & 3;                      // t2 group split: b=0 on xcd=qtr, b=1 on xcd=qtr+4
        b = xcd >> 2;
        ti = local - 42;
    }

    int nTot = startPad[b * (NSEL + 1) + NSEL];
    if (ti * 64 >= nTot) return;
    int sel = rowc[b * NP + ti * 64];
    const unsigned short* XcT = Xc + ((size_t)t * BQ + b) * NN * DMD;
    const unsigned short* L = Lt + (size_t)(t * NSEL + sel) * DMD * 512;   // [n][k] bf16

    __shared__ __align__(16) unsigned short Xb[64][72];
    __shared__ __align__(16) unsigned short Lb[128][72];
    __shared__ int toks[64];

    int tid = threadIdx.x;
    int wave = tid >> 6, lane = tid & 63;
    int m = lane & 15, q = lane >> 4;
    if (tid < 64) toks[tid] = perm[b * NP + ti * 64 + tid];
    __syncthreads();

    int xr = tid >> 2, xc0 = (tid & 3) * 16;
    int xtok = toks[xr];
    const unsigned short* xbase = (xtok >= 0) ? &XcT[(size_t)xtok * DMD] : (const unsigned short*)0;
    int ln = tid >> 1, lhf = tid & 1;
    const unsigned short* lbase = &L[(size_t)(qtr * 128 + ln) * 512 + lhf * 32];

    u16x8 rx0 = {0, 0, 0, 0, 0, 0, 0, 0}, rx1 = {0, 0, 0, 0, 0, 0, 0, 0};
    u16x8 rl0, rl1, rl2, rl3;
    if (xbase) { rx0 = *(const u16x8*)&xbase[xc0]; rx1 = *(const u16x8*)&xbase[xc0 + 8]; }
    rl0 = *(const u16x8*)&lbase[0];  rl1 = *(const u16x8*)&lbase[8];
    rl2 = *(const u16x8*)&lbase[16]; rl3 = *(const u16x8*)&lbase[24];

    f32x4 acc[4][2];
#pragma unroll
    for (int mt = 0; mt < 4; mt++) { acc[mt][0] = {0, 0, 0, 0}; acc[mt][1] = {0, 0, 0, 0}; }

    for (int kb = 0; kb < DMD; kb += 64) {
        *(u16x8*)&Xb[xr][xc0] = rx0;
        *(u16x8*)&Xb[xr][xc0 + 8] = rx1;
        *(u16x8*)&Lb[ln][lhf * 32 + 0]  = rl0;
        *(u16x8*)&Lb[ln][lhf * 32 + 8]  = rl1;
        *(u16x8*)&Lb[ln][lhf * 32 + 16] = rl2;
        *(u16x8*)&Lb[ln][lhf * 32 + 24] = rl3;
        __syncthreads();
        if (kb + 64 < DMD) {   // prefetch next slab (overlaps MFMAs)
            int nk = kb + 64;
            if (xbase) { rx0 = *(const u16x8*)&xbase[nk + xc0]; rx1 = *(const u16x8*)&xbase[nk + xc0 + 8]; }
            rl0 = *(const u16x8*)&lbase[nk];      rl1 = *(const u16x8*)&lbase[nk + 8];
            rl2 = *(const u16x8*)&lbase[nk + 16]; rl3 = *(const u16x8*)&lbase[nk + 24];
        }
#pragma unroll
        for (int kc = 0; kc < 64; kc += 32) {
            bf16x8 bf0 = *(const bf16x8*)&Lb[wave * 32 + m][kc + q * 8];
            bf16x8 bf1 = *(const bf16x8*)&Lb[wave * 32 + 16 + m][kc + q * 8];
#pragma unroll
            for (int mt = 0; mt < 4; mt++) {
                bf16x8 a = *(const bf16x8*)&Xb[mt * 16 + m][kc + q * 8];
                acc[mt][0] = __builtin_amdgcn_mfma_f32_16x16x32_bf16(a, bf0, acc[mt][0], 0, 0, 0);
                acc[mt][1] = __builtin_amdgcn_mfma_f32_16x16x32_bf16(a, bf1, acc[mt][1], 0, 0, 0);
            }
        }
        __syncthreads();
    }

    if (t < 2) {
        unsigned short* O = (t == 0) ? Qb : Kb;
#pragma unroll
        for (int mt = 0; mt < 4; mt++)
#pragma unroll
            for (int nt = 0; nt < 2; nt++)
#pragma unroll
                for (int gg = 0; gg < 4; gg++) {
                    int i = mt * 16 + q * 4 + gg;
                    int hk = qtr * 128 + wave * 32 + nt * 16 + m;
                    int h = hk >> 6, k0 = hk & 63;
                    O[(((size_t)b * NH + h) * NP + ti * 64 + i) * 64 + k0] = f2bf(acc[mt][nt][gg]);
                }
    } else {
        // stage V tile into Lb as Vs[hl*64+jp][d] (Lb dead after main loop)
#pragma unroll
        for (int mt = 0; mt < 4; mt++)
#pragma unroll
            for (int nt = 0; nt < 2; nt++)
#pragma unroll
                for (int gg = 0; gg < 4; gg++) {
                    int jp = mt * 16 + q * 4 + gg;
                    int hl = wave >> 1;
                    int d = (wave & 1) * 32 + nt * 16 + m;
                    Lb[hl * 64 + jp][d] = f2bf(acc[mt][nt][gg]);
                }
        __syncthreads();
        // V2t[r][bh][k][jp] = sum_d W2bt[cls(r,sel)][h][k][d] * V[jp][d]; wave = k-subtile
        int kw = wave;
        for (int r = 0; r < NSEL; r++) {
            int cls = clsOf(r, sel);
#pragma unroll
            for (int hl = 0; hl < 2; hl++) {
                int h = qtr * 2 + hl;
                const unsigned short* ap = W2bt + (((size_t)cls * NH + h) << 12)
                                         + (size_t)(kw * 16 + m) * 64 + q * 8;
                bf16x8 a0 = *(const bf16x8*)ap;
                bf16x8 a1 = *(const bf16x8*)(ap + 32);
                unsigned short* Cb = V2t + ((size_t)r * 16 + b * NH + h) * 64 * NP;
#pragma unroll
                for (int nb = 0; nb < 4; nb++) {
                    bf16x8 b0 = *(const bf16x8*)&Lb[hl * 64 + nb * 16 + m][q * 8];
                    bf16x8 b1 = *(const bf16x8*)&Lb[hl * 64 + nb * 16 + m][q * 8 + 32];
                    f32x4 a2 = {0.f, 0.f, 0.f, 0.f};
                    a2 = __builtin_amdgcn_mfma_f32_16x16x32_bf16(a0, b0, a2, 0, 0, 0);
                    a2 = __builtin_amdgcn_mfma_f32_16x16x32_bf16(a1, b1, a2, 0, 0, 0);
#pragma unroll
                    for (int gg = 0; gg < 4; gg++)
                        Cb[(size_t)(kw * 16 + q * 4 + gg) * NP + ti * 64 + nb * 16 + m] = f2bf(a2[gg]);
                }
            }
        }
    }
}

// ---------------------------------------------------------------- fused attention: 512 threads, XCD-swizzled, LDS union
// LDS ~51.4 KB -> 3 blocks/CU (24 waves). qloc aliases S (dead before first S write).
__global__ __launch_bounds__(512, 4) void k_attn(
    const unsigned short* __restrict__ Qb, const unsigned short* __restrict__ Kb,
    const unsigned short* __restrict__ V2t, const unsigned short* __restrict__ W1bt,
    const int* __restrict__ perm, const int* __restrict__ rowc, const int* __restrict__ startPad,
    const int* __restrict__ maskI, const int* __restrict__ maskP,
    float* __restrict__ out)
{
    int bid = blockIdx.x;
    int xcd = bid & 7, local = bid >> 3;          // 0..167
    int bh = xcd * 2 + (local >= 84 ? 1 : 0);
    int it = (local >= 84) ? (local - 84) : local;
    int b = bh >> 3, h = bh & 7;
    int nTot = startPad[b * (NSEL + 1) + NSEL];
    int i0 = it * 16;
    if (i0 >= nTot) return;
    int r = rowc[b * NP + i0];
    int tiles = nTot >> 6;

    // ---- LDS union layout (total 52564 B)
    __shared__ __align__(16) char smem[16 * SSp * 2 + 8192 + 1024 + 4 * (NPT + 16 + 16)];
    unsigned short (*S)[SSp] = (unsigned short (*)[SSp])smem;                 // phases 2-3
    unsigned short (*qloc)[16][QLS] = (unsigned short (*)[16][QLS])smem;      // phases 0b-1 (aliases S)
    float (*pbuf)[16][64] = (float (*)[16][64])(smem + 16 * SSp * 2);         // 8192 B
    float (*wred)[16] = (float (*)[16])(smem + 16 * SSp * 2 + 8192);          // 512 B
    float (*wsum)[16] = (float (*)[16])(smem + 16 * SSp * 2 + 8192 + 512);    // 512 B
    int* tilec = (int*)(smem + 16 * SSp * 2 + 8192 + 1024);
    int* mrow = tilec + NPT;
    int* toki = mrow + 16;

    int tid = threadIdx.x;
    int wave = tid >> 6, lane = tid & 63;
    int m = lane & 15, q = lane >> 4;

    const int* permB = perm + b * NP;
    const unsigned short* QbB = Qb + (size_t)bh * NP * 64;
    const unsigned short* KbB = Kb + (size_t)bh * NP * 64;
    const unsigned short* V2B = V2t + ((size_t)r * 16 + bh) * 64 * NP; // [k][jp]
    const int* maskPB = maskP + b * NP;

    if (tid < NPT) tilec[tid] = rowc[b * NP + tid * 64];
    else if (tid >= 64 && tid < 80) {
        int rr = tid - 64;
        int tok = permB[i0 + rr];
        toki[rr] = tok;
        mrow[rr] = (tok >= 0) ? maskI[b * NN + tok] : 0;
    }

    // ---- phase 0b: qloc[c][i][n] = Q . W1m[cls(r,c)]; 8 waves = {c-half} x {n-subtile}
    {
        const unsigned short* qa = &QbB[(size_t)(i0 + m) * 64 + q * 8];
        bf16x8 a0 = *(const bf16x8*)qa;
        bf16x8 a1 = *(const bf16x8*)(qa + 32);
        int sub = wave & 3;
        int c0 = (wave >> 2) ? 3 : 0;
        int c1 = (wave >> 2) ? 5 : 3;
        for (int c = c0; c < c1; c++) {
            int cls = clsOf(r, c);
            const unsigned short* wb = W1bt + (((size_t)cls * NH + h) << 12)
                                     + (size_t)(sub * 16 + m) * 64 + q * 8;
            bf16x8 b0 = *(const bf16x8*)wb;
            bf16x8 b1 = *(const bf16x8*)(wb + 32);
            f32x4 acc = {0.f, 0.f, 0.f, 0.f};
            acc = __builtin_amdgcn_mfma_f32_16x16x32_bf16(a0, b0, acc, 0, 0, 0);
            acc = __builtin_amdgcn_mfma_f32_16x16x32_bf16(a1, b1, acc, 0, 0, 0);
#pragma unroll
            for (int g = 0; g < 4; g++)
                qloc[c][q * 4 + g][sub * 16 + m] = f2bf(acc[g]);
        }
    }
    __syncthreads();

    // ---- phase 1: scores in registers (wave stride 8 over j-tiles)
    float sarr[MAXT][4][4];
    float lmax[4] = {-INFINITY, -INFINITY, -INFINITY, -INFINITY};
    int mrow4[4];
#pragma unroll
    for (int g = 0; g < 4; g++) mrow4[g] = mrow[q * 4 + g];

#pragma unroll
    for (int tt = 0; tt < MAXT; tt++) {
        int jt = wave + tt * 8;
        bool valid = (jt < tiles);
        int jts = valid ? jt : 0;
        int c = tilec[jts];
        int jb = jts * 64;
        const unsigned short* qa = &qloc[c][m][q * 8];
        bf16x8 a0 = *(const bf16x8*)qa;
        bf16x8 a1 = *(const bf16x8*)(qa + 32);
#pragma unroll
        for (int nb = 0; nb < 4; nb++) {
            int j = jb + nb * 16 + m;
            const unsigned short* kb = &KbB[(size_t)j * 64 + q * 8];
            bf16x8 b0 = *(const bf16x8*)kb;
            bf16x8 b1 = *(const bf16x8*)(kb + 32);
            f32x4 acc = {0.f, 0.f, 0.f, 0.f};
            acc = __builtin_amdgcn_mfma_f32_16x16x32_bf16(a0, b0, acc, 0, 0, 0);
            acc = __builtin_amdgcn_mfma_f32_16x16x32_bf16(a1, b1, acc, 0, 0, 0);
            int mj = maskPB[j];
#pragma unroll
            for (int g = 0; g < 4; g++) {
                float sv;
                if (!valid || mj == 2)   sv = -INFINITY;      // padding / no tile
                else if (mrow4[g] && mj) sv = acc[g] * 0.125f;
                else                     sv = -1e30f;         // reference's masked value
                sarr[tt][nb][g] = sv;
                lmax[g] = fmaxf(lmax[g], sv);
            }
        }
    }
#pragma unroll
    for (int g = 0; g < 4; g++) {
        float v = lmax[g];
#pragma unroll
        for (int o = 1; o < 16; o <<= 1) v = fmaxf(v, __shfl_xor(v, o));
        lmax[g] = v;
    }
    if (m == 0) {
#pragma unroll
        for (int g = 0; g < 4; g++) wred[wave][q * 4 + g] = lmax[g];
    }
    __syncthreads();   // qloc dead from here; S region reusable

    // ---- phase 2: exp in regs, single P write into S, row sums
    float mx4[4], lsum[4] = {0.f, 0.f, 0.f, 0.f};
#pragma unroll
    for (int g = 0; g < 4; g++) {
        int i = q * 4 + g;
        float v = wred[0][i];
#pragma unroll
        for (int w2 = 1; w2 < 8; w2++) v = fmaxf(v, wred[w2][i]);
        mx4[g] = v;
    }
#pragma unroll
    for (int tt = 0; tt < MAXT; tt++) {
        int jt = wave + tt * 8;
        bool valid = (jt < tiles);
        int jb = jt * 64;
#pragma unroll
        for (int nb = 0; nb < 4; nb++) {
            int j = jb + nb * 16 + m;
#pragma unroll
            for (int g = 0; g < 4; g++) {
                float p = __expf(sarr[tt][nb][g] - mx4[g]);   // -inf -> 0
                lsum[g] += p;
                if (valid) S[q * 4 + g][j] = f2bf(p);
            }
        }
    }
#pragma unroll
    for (int g = 0; g < 4; g++) {
        float v = lsum[g];
#pragma unroll
        for (int o = 1; o < 16; o <<= 1) v += __shfl_xor(v, o);
        lsum[g] = v;
    }
    if (m == 0) {
#pragma unroll
        for (int g = 0; g < 4; g++) wsum[wave][q * 4 + g] = lsum[g];
    }
    __syncthreads();

    // ---- phase 3: out = P . V2t^T ; wave (kw,p): k-subtile kw, j-parity p
    {
        int kw = wave & 3, p = wave >> 2;
        int db = kw * 16;
        f32x4 ae = {0.f, 0.f, 0.f, 0.f};
        f32x4 ao = {0.f, 0.f, 0.f, 0.f};
        for (int jt = p; jt < tiles; jt += 2) {
            int jb = jt * 64;
            bf16x8 a0 = *(const bf16x8*)&S[m][jb + q * 8];
            bf16x8 a1 = *(const bf16x8*)&S[m][jb + 32 + q * 8];
            const unsigned short* vb = V2B + (size_t)(db + m) * NP + jb + q * 8;
            bf16x8 b0 = *(const bf16x8*)vb;
            bf16x8 b1 = *(const bf16x8*)(vb + 32);
            ae = __builtin_amdgcn_mfma_f32_16x16x32_bf16(a0, b0, ae, 0, 0, 0);
            ao = __builtin_amdgcn_mfma_f32_16x16x32_bf16(a1, b1, ao, 0, 0, 0);
        }
#pragma unroll
        for (int g = 0; g < 4; g++)
            pbuf[p][q * 4 + g][db + m] = ae[g] + ao[g];
    }
    __syncthreads();

    // ---- epilogue: combine parities, normalize, store
    for (int idx = tid; idx < 16 * 64; idx += 512) {
        int i = idx >> 6, k = idx & 63;
        int tok = toki[i];
        if (tok >= 0) {
            float s = wsum[0][i] + wsum[1][i] + wsum[2][i] + wsum[3][i]
                    + wsum[4][i] + wsum[5][i] + wsum[6][i] + wsum[7][i];
            float v = pbuf[0][i][k] + pbuf[1][i][k];
            out[((size_t)b * NN + tok) * (NH * DKK) + h * DKK + k] = v / s;
        }
    }
}

// ---------------------------------------------------------------- launch
extern "C" void kernel_launch(void* const* d_in, const int* in_sizes, int n_in,
                              void* d_out, int out_size, void* d_ws, size_t ws_size,
                              hipStream_t stream)
{
    const float* qr  = (const float*)d_in[0];
    const float* kr  = (const float*)d_in[1];
    const float* vr  = (const float*)d_in[2];
    const void* bsr  = d_in[3];
    const void* mkr  = d_in[4];
    const float* lr  = (const float*)d_in[5];
    const float* w1r = (const float*)d_in[6];
    const float* a1r = (const float*)d_in[7];
    const float* w2r = (const float*)d_in[8];
    const float* a2r = (const float*)d_in[9];
    float* out = (float*)d_out;

    char* w = (char*)d_ws;
    int* maskI    = (int*)w;
    int* perm     = maskI + BQ * NN;
    int* rowc     = perm + BQ * NP;
    int* startPad = rowc + BQ * NP;
    int* maskP    = startPad + 12;
    unsigned short* W1bt = (unsigned short*)(w + 65536);
    unsigned short* W2bt = W1bt + (size_t)NCLS * NH * 4096;
    unsigned short* Qb   = (unsigned short*)(w + 2359296);
    unsigned short* Kb   = Qb + (size_t)BQ * NH * NP * 64;
    unsigned short* Lt   = (unsigned short*)(w + 10616832);
    unsigned short* V2t  = (unsigned short*)(w + 24379392);
    unsigned short* Xc   = (unsigned short*)(w + 38141952);          // total ~44.4 MB

    hipLaunchKernelGGL(k_prep, dim3(960 + 2 * NCLS * NH + 96 + 1), dim3(256), 0, stream,
                       lr, Lt, w1r, w2r, a1r, a2r, W1bt, W2bt, qr, kr, vr, Xc,
                       bsr, mkr, maskI, perm, rowc, startPad, maskP);
    hipLaunchKernelGGL(k_proj, dim3(504), dim3(256), 0, stream,
                       Xc, Lt, W2bt, perm, rowc, startPad, Qb, Kb, V2t);
    hipLaunchKernelGGL(k_attn, dim3(8 * 2 * 84), dim3(512), 0, stream,
                       Qb, Kb, V2t, W1bt, perm, rowc, startPad, maskI, maskP, out);
}

// Round 12
// 184.212 us; speedup vs baseline: 1.1982x; 1.0218x over previous
//
#include <hip/hip_runtime.h>
#include <hip/hip_bf16.h>
#include <math.h>

#define BQ   2      // batch
#define NN   1024   // seq len
#define DMD  512    // d_model
#define NH   8      // heads
#define DKK  64     // head dim
#define NSEL 5      // NB+1 block values (0..4)
#define NCLS 17     // block-pair classes
#define NP   1344   // padded per-batch capacity (buckets padded to 64)
#define NPT  21     // NP/64 tiles
#define MAXT 3      // max key-tiles per wave in k_attn (ceil(21/8))
#define SSp  1348   // S row stride (shorts): conflict-free
#define QLS  68     // qloc/u row stride (shorts)

typedef __attribute__((ext_vector_type(8))) short bf16x8;
typedef __attribute__((ext_vector_type(8))) unsigned short u16x8;
typedef __attribute__((ext_vector_type(4))) float f32x4;

__device__ __forceinline__ int clsOf(int r, int c) { return (r == 0 || c == 0) ? 0 : ((r - 1) * 4 + c); }

__device__ __forceinline__ unsigned short f2bf(float x) {
    __hip_bfloat16 h = __float2bfloat16(x);
    return *reinterpret_cast<unsigned short*>(&h);
}

// ---------------------------------------------------------------- prep: lin cast (960) + wmix (272) + qkv cast (96) + setup (1)
__global__ __launch_bounds__(256) void k_prep(
    const float* __restrict__ lr, unsigned short* __restrict__ Lt,
    const float* __restrict__ W1, const float* __restrict__ W2,
    const float* __restrict__ al1, const float* __restrict__ al2,
    unsigned short* __restrict__ W1bt, unsigned short* __restrict__ W2bt,
    const float* __restrict__ qr, const float* __restrict__ kr, const float* __restrict__ vr,
    unsigned short* __restrict__ Xc,
    const void* __restrict__ b_seq_r, const void* __restrict__ mask_r,
    int* __restrict__ maskI, int* __restrict__ perm, int* __restrict__ rowc,
    int* __restrict__ startPad, int* __restrict__ maskP)
{
    __shared__ float Tf[64][68];
    __shared__ int det[5];
    __shared__ int cnts[BQ][NSEL];
    __shared__ int offs[BQ][NSEL];
    __shared__ int sstart[BQ][NSEL + 1];
    int bx = blockIdx.x;
    int tid = threadIdx.x;
    if (bx < 960) {
        // cast+transpose lin[ts][k][n] -> Lt[ts][n][k] bf16
        int ts = bx >> 6, rem = bx & 63;
        int kt = rem >> 3, nt = rem & 7;
        const float* src = lr + (size_t)ts * DMD * 512;
        unsigned short* dst = Lt + (size_t)ts * DMD * 512;
        int r = tid >> 2, c4 = tid & 3;
#pragma unroll
        for (int i = 0; i < 4; i++) {
            float4 v = *(const float4*)&src[(size_t)(kt * 64 + r) * 512 + nt * 64 + c4 * 16 + i * 4];
            *(float4*)&Tf[r][c4 * 16 + i * 4] = v;
        }
        __syncthreads();
        unsigned short tmp[16];
#pragma unroll
        for (int i = 0; i < 16; i++) tmp[i] = f2bf(Tf[c4 * 16 + i][r]);
        u16x8 o0, o1;
#pragma unroll
        for (int i = 0; i < 8; i++) { o0[i] = tmp[i]; o1[i] = tmp[8 + i]; }
        unsigned short* dp = &dst[(size_t)(nt * 64 + r) * 512 + kt * 64 + c4 * 16];
        *(u16x8*)&dp[0] = o0;
        *(u16x8*)&dp[8] = o1;
    } else if (bx < 960 + 2 * NCLS * NH) {
        int bid = bx - 960;
        int w = bid / (NCLS * NH);
        int rem = bid % (NCLS * NH);
        int c = rem / NH, h = rem % NH;
        const float* W = w ? W2 : W1;
        const float* a = w ? al2 : al1;
        unsigned short* outp = (w ? W2bt : W1bt) + (((size_t)c * NH + h) << 12);
        float vals[4], mx = -1e30f;
#pragma unroll
        for (int bb = 0; bb < 4; bb++) { vals[bb] = a[(c * 4 + bb) * NH + h]; mx = fmaxf(mx, vals[bb]); }
        float ssum = 0.f;
#pragma unroll
        for (int bb = 0; bb < 4; bb++) { vals[bb] = __expf(vals[bb] - mx); ssum += vals[bb]; }
        float inv = 1.0f / ssum;
        float s0 = vals[0] * inv, s1 = vals[1] * inv, s2 = vals[2] * inv, s3 = vals[3] * inv;
        const float* p0 = W + (size_t)(0 * NH + h) * 4096;
        const float* p1 = W + (size_t)(1 * NH + h) * 4096;
        const float* p2 = W + (size_t)(2 * NH + h) * 4096;
        const float* p3 = W + (size_t)(3 * NH + h) * 4096;
        for (int e = tid; e < 4096; e += 256) {
            float v = s0 * p0[e] + s1 * p1[e] + s2 * p2[e] + s3 * p3[e];
            int mm = e >> 6, nn = e & 63;
            outp[nn * 64 + mm] = f2bf(v);     // transposed store
        }
    } else if (bx < 960 + 2 * NCLS * NH + 96) {
        // cast q/k/v -> Xc bf16 [t][b][n][512]
        int bid = bx - (960 + 2 * NCLS * NH);   // 0..95
        int t = bid / 32, rem = bid % 32;
        int b = rem / 16, rg = rem % 16;
        int row = tid >> 2, part = tid & 3;
        const float* X = (t == 0) ? qr : ((t == 1) ? kr : vr);
        const float* src = X + ((size_t)b * NN + rg * 64 + row) * DMD + part * 128;
        unsigned short* dst = Xc + (((size_t)t * BQ + b) * NN + rg * 64 + row) * DMD + part * 128;
#pragma unroll
        for (int i = 0; i < 128; i += 8) {
            float4 v0 = *(const float4*)&src[i];
            float4 v1 = *(const float4*)&src[i + 4];
            u16x8 o;
            o[0] = f2bf(v0.x); o[1] = f2bf(v0.y); o[2] = f2bf(v0.z); o[3] = f2bf(v0.w);
            o[4] = f2bf(v1.x); o[5] = f2bf(v1.y); o[6] = f2bf(v1.z); o[7] = f2bf(v1.w);
            *(u16x8*)&dst[i] = o;
        }
    } else {
        // ---- setup (single block): dtype detect, bucketize, perm, masks
        if (tid < 5) det[tid] = 0;
        if (tid < BQ * NSEL) { cnts[tid / NSEL][tid % NSEL] = 0; offs[tid / NSEL][tid % NSEL] = 0; }
        __syncthreads();
        const int* b32 = (const int*)b_seq_r;
        const unsigned char* mb = (const unsigned char*)mask_r;
        const int* m32 = (const int*)mask_r;
        if (tid < 64) {
            if (b32[2 * tid + 1] != 0) atomicOr(&det[0], 1);
            if (b32[2 * tid] != 0)     atomicOr(&det[1], 1);
            if (m32[2 * tid + 1] != 0) atomicOr(&det[3], 1);
            if (m32[2 * tid] != 0)     atomicOr(&det[4], 1);
        }
        if ((tid & 3) != 0 && mb[tid] != 0) atomicOr(&det[2], 1);
        __syncthreads();
        int bsI64 = (det[0] == 0 && det[1] != 0);
        int mk = det[2] ? 1 : ((det[3] == 0 && det[4] != 0) ? 2 : 0);

        for (int g = tid; g < BQ * NN; g += 256) {
            int m = (mk == 1) ? (mb[g] != 0) : ((mk == 2) ? (m32[2 * g] != 0) : (m32[g] != 0));
            maskI[g] = m;
            int bs = bsI64 ? b32[2 * g] : b32[g];
            bs = bs < 0 ? 0 : (bs > 4 ? 4 : bs);
            atomicAdd(&cnts[g / NN][bs], 1);
        }
        __syncthreads();
        if (tid == 0) {
            for (int b = 0; b < BQ; b++) {
                int acc = 0;
                for (int c = 0; c < NSEL; c++) {
                    sstart[b][c] = acc;
                    acc += ((cnts[b][c] + 63) / 64) * 64;
                }
                sstart[b][NSEL] = acc;
                for (int c = 0; c <= NSEL; c++) startPad[b * (NSEL + 1) + c] = sstart[b][c];
            }
        }
        __syncthreads();
        for (int g = tid; g < BQ * NP; g += 256) {
            perm[g] = -1;
            int b = g / NP, sslot = g % NP;
            int c = 0;
            for (int cc = 1; cc < NSEL; cc++) if (sslot >= sstart[b][cc]) c = cc;
            rowc[g] = c;
        }
        __syncthreads();
        for (int g = tid; g < BQ * NN; g += 256) {
            int b = g / NN, n = g % NN;
            int bs = bsI64 ? b32[2 * g] : b32[g];
            bs = bs < 0 ? 0 : (bs > 4 ? 4 : bs);
            int pos = sstart[b][bs] + atomicAdd(&offs[b][bs], 1);
            perm[b * NP + pos] = n;
        }
        __syncthreads();
        for (int g = tid; g < BQ * NP; g += 256) {
            int tok = perm[g];
            maskP[g] = (tok < 0) ? 2 : maskI[(g / NP) * NN + tok];
        }
    }
}

// ---------------------------------------------------------------- QKV projection, MFMA bf16, XCD-aligned with k_attn
// 504 blocks = 8 XCDs x (3 t x 21 ti); qtr = xcd&3, b = xcd>>2.
// Each XCD writes Qb/Kb/Vt for exactly the 2 (b,h) pairs its k_attn blocks read.
__global__ __launch_bounds__(256) void k_proj(
    const unsigned short* __restrict__ Xc,
    const unsigned short* __restrict__ Lt,
    const int* __restrict__ perm, const int* __restrict__ rowc, const int* __restrict__ startPad,
    unsigned short* __restrict__ Qb, unsigned short* __restrict__ Kb,
    unsigned short* __restrict__ Vt)
{
    int bid = blockIdx.x;
    int xcd = bid & 7, local = bid >> 3;          // 0..62
    int t = local / 21, ti = local % 21;
    int qtr = xcd & 3, b = xcd >> 2;

    int nTot = startPad[b * (NSEL + 1) + NSEL];
    if (ti * 64 >= nTot) return;
    int sel = rowc[b * NP + ti * 64];
    const unsigned short* XcT = Xc + ((size_t)t * BQ + b) * NN * DMD;
    const unsigned short* L = Lt + (size_t)(t * NSEL + sel) * DMD * 512;   // [n][k] bf16

    __shared__ __align__(16) unsigned short Xb[64][72];
    __shared__ __align__(16) unsigned short Lb[128][72];
    __shared__ int toks[64];

    int tid = threadIdx.x;
    int wave = tid >> 6, lane = tid & 63;
    int m = lane & 15, q = lane >> 4;
    if (tid < 64) toks[tid] = perm[b * NP + ti * 64 + tid];
    __syncthreads();

    int xr = tid >> 2, xc0 = (tid & 3) * 16;
    int xtok = toks[xr];
    const unsigned short* xbase = (xtok >= 0) ? &XcT[(size_t)xtok * DMD] : (const unsigned short*)0;
    int ln = tid >> 1, lhf = tid & 1;
    const unsigned short* lbase = &L[(size_t)(qtr * 128 + ln) * 512 + lhf * 32];

    u16x8 rx0 = {0, 0, 0, 0, 0, 0, 0, 0}, rx1 = {0, 0, 0, 0, 0, 0, 0, 0};
    u16x8 rl0, rl1, rl2, rl3;
    if (xbase) { rx0 = *(const u16x8*)&xbase[xc0]; rx1 = *(const u16x8*)&xbase[xc0 + 8]; }
    rl0 = *(const u16x8*)&lbase[0];  rl1 = *(const u16x8*)&lbase[8];
    rl2 = *(const u16x8*)&lbase[16]; rl3 = *(const u16x8*)&lbase[24];

    f32x4 acc[4][2];
#pragma unroll
    for (int mt = 0; mt < 4; mt++) { acc[mt][0] = {0, 0, 0, 0}; acc[mt][1] = {0, 0, 0, 0}; }

    for (int kb = 0; kb < DMD; kb += 64) {
        *(u16x8*)&Xb[xr][xc0] = rx0;
        *(u16x8*)&Xb[xr][xc0 + 8] = rx1;
        *(u16x8*)&Lb[ln][lhf * 32 + 0]  = rl0;
        *(u16x8*)&Lb[ln][lhf * 32 + 8]  = rl1;
        *(u16x8*)&Lb[ln][lhf * 32 + 16] = rl2;
        *(u16x8*)&Lb[ln][lhf * 32 + 24] = rl3;
        __syncthreads();
        if (kb + 64 < DMD) {   // prefetch next slab (overlaps MFMAs)
            int nk = kb + 64;
            if (xbase) { rx0 = *(const u16x8*)&xbase[nk + xc0]; rx1 = *(const u16x8*)&xbase[nk + xc0 + 8]; }
            rl0 = *(const u16x8*)&lbase[nk];      rl1 = *(const u16x8*)&lbase[nk + 8];
            rl2 = *(const u16x8*)&lbase[nk + 16]; rl3 = *(const u16x8*)&lbase[nk + 24];
        }
#pragma unroll
        for (int kc = 0; kc < 64; kc += 32) {
            bf16x8 bf0 = *(const bf16x8*)&Lb[wave * 32 + m][kc + q * 8];
            bf16x8 bf1 = *(const bf16x8*)&Lb[wave * 32 + 16 + m][kc + q * 8];
#pragma unroll
            for (int mt = 0; mt < 4; mt++) {
                bf16x8 a = *(const bf16x8*)&Xb[mt * 16 + m][kc + q * 8];
                acc[mt][0] = __builtin_amdgcn_mfma_f32_16x16x32_bf16(a, bf0, acc[mt][0], 0, 0, 0);
                acc[mt][1] = __builtin_amdgcn_mfma_f32_16x16x32_bf16(a, bf1, acc[mt][1], 0, 0, 0);
            }
        }
        __syncthreads();
    }

    if (t < 2) {
        unsigned short* O = (t == 0) ? Qb : Kb;
#pragma unroll
        for (int mt = 0; mt < 4; mt++)
#pragma unroll
            for (int nt = 0; nt < 2; nt++)
#pragma unroll
                for (int gg = 0; gg < 4; gg++) {
                    int i = mt * 16 + q * 4 + gg;
                    int hk = qtr * 128 + wave * 32 + nt * 16 + m;
                    int h = hk >> 6, k0 = hk & 63;
                    O[(((size_t)b * NH + h) * NP + ti * 64 + i) * 64 + k0] = f2bf(acc[mt][nt][gg]);
                }
    } else {
        // transpose via Lb (dead), write Vt[b][h][d][ip] coalesced
#pragma unroll
        for (int mt = 0; mt < 4; mt++)
#pragma unroll
            for (int nt = 0; nt < 2; nt++)
#pragma unroll
                for (int gg = 0; gg < 4; gg++)
                    Lb[wave * 32 + nt * 16 + m][mt * 16 + q * 4 + gg] = f2bf(acc[mt][nt][gg]);
        __syncthreads();
        int hkl = tid >> 1, hf = tid & 1;
        int hk = qtr * 128 + hkl;
        int h = hk >> 6, d = hk & 63;
        unsigned short* vp = Vt + (((size_t)b * NH + h) * DKK + d) * NP + ti * 64 + hf * 32;
#pragma unroll
        for (int s = 0; s < 4; s++)
            *(u16x8*)&vp[s * 8] = *(const u16x8*)&Lb[hkl][hf * 32 + s * 8];
    }
}

// ---------------------------------------------------------------- fused attention: 512 threads, XCD-swizzled
// Phases: 0b Q·W1 -> qloc | 1 scores (reg) | 2 softmax -> S | 3 per-class PV -> u | 4 u·W2 -> out
__global__ __launch_bounds__(512, 4) void k_attn(
    const unsigned short* __restrict__ Qb, const unsigned short* __restrict__ Kb,
    const unsigned short* __restrict__ Vt, const unsigned short* __restrict__ W1bt,
    const unsigned short* __restrict__ W2bt,
    const int* __restrict__ perm, const int* __restrict__ rowc, const int* __restrict__ startPad,
    const int* __restrict__ maskI, const int* __restrict__ maskP,
    float* __restrict__ out)
{
    int bid = blockIdx.x;
    int xcd = bid & 7, local = bid >> 3;          // 0..167
    int bh = xcd * 2 + (local >= 84 ? 1 : 0);
    int it = (local >= 84) ? (local - 84) : local;
    int b = bh >> 3, h = bh & 7;
    int nTot = startPad[b * (NSEL + 1) + NSEL];
    int i0 = it * 16;
    if (i0 >= nTot) return;
    int r = rowc[b * NP + i0];
    int tiles = nTot >> 6;

    // ---- LDS union (55276 B): S | u | wred | wsum | tilec | cstart | mrow | toki
    __shared__ __align__(16) char smem[16 * SSp * 2 + NSEL * 16 * QLS * 2 + 1024 + 4 * (NPT + 6 + 16 + 16)];
    unsigned short (*S)[SSp] = (unsigned short (*)[SSp])smem;                 // phases 2-3
    unsigned short (*qloc)[16][QLS] = (unsigned short (*)[16][QLS])smem;      // phases 0b-1 (aliases S)
    float (*pbuf)[16][64] = (float (*)[16][64])smem;                          // phase 4 (aliases S)
    unsigned short (*u)[16][QLS] = (unsigned short (*)[16][QLS])(smem + 16 * SSp * 2);
    char* tail = smem + 16 * SSp * 2 + NSEL * 16 * QLS * 2;
    float (*wred)[16] = (float (*)[16])tail;
    float (*wsum)[16] = (float (*)[16])(tail + 512);
    int* tilec = (int*)(tail + 1024);
    int* cstart = tilec + NPT;
    int* mrow = cstart + 6;
    int* toki = mrow + 16;

    int tid = threadIdx.x;
    int wave = tid >> 6, lane = tid & 63;
    int m = lane & 15, q = lane >> 4;

    const int* permB = perm + b * NP;
    const unsigned short* QbB = Qb + (size_t)bh * NP * 64;
    const unsigned short* KbB = Kb + (size_t)bh * NP * 64;
    const unsigned short* VtB = Vt + (size_t)bh * DKK * NP;      // [d][jp]
    const int* maskPB = maskP + b * NP;

    if (tid < NPT) tilec[tid] = rowc[b * NP + tid * 64];
    else if (tid >= 32 && tid < 38) cstart[tid - 32] = startPad[b * (NSEL + 1) + (tid - 32)];
    else if (tid >= 64 && tid < 80) {
        int rr = tid - 64;
        int tok = permB[i0 + rr];
        toki[rr] = tok;
        mrow[rr] = (tok >= 0) ? maskI[b * NN + tok] : 0;
    }

    // ---- phase 0b: qloc[c][i][n] = Q . W1m[cls(r,c)]; 8 waves = {c-half} x {n-subtile}
    {
        const unsigned short* qa = &QbB[(size_t)(i0 + m) * 64 + q * 8];
        bf16x8 a0 = *(const bf16x8*)qa;
        bf16x8 a1 = *(const bf16x8*)(qa + 32);
        int sub = wave & 3;
        int c0 = (wave >> 2) ? 3 : 0;
        int c1 = (wave >> 2) ? 5 : 3;
        for (int c = c0; c < c1; c++) {
            int cls = clsOf(r, c);
            const unsigned short* wb = W1bt + (((size_t)cls * NH + h) << 12)
                                     + (size_t)(sub * 16 + m) * 64 + q * 8;
            bf16x8 b0 = *(const bf16x8*)wb;
            bf16x8 b1 = *(const bf16x8*)(wb + 32);
            f32x4 acc = {0.f, 0.f, 0.f, 0.f};
            acc = __builtin_amdgcn_mfma_f32_16x16x32_bf16(a0, b0, acc, 0, 0, 0);
            acc = __builtin_amdgcn_mfma_f32_16x16x32_bf16(a1, b1, acc, 0, 0, 0);
#pragma unroll
            for (int g = 0; g < 4; g++)
                qloc[c][q * 4 + g][sub * 16 + m] = f2bf(acc[g]);
        }
    }
    __syncthreads();

    // ---- phase 1: scores in registers; batch all 8 K loads per tile before the MFMA burst
    float sarr[MAXT][4][4];
    float lmax[4] = {-INFINITY, -INFINITY, -INFINITY, -INFINITY};
    int mrow4[4];
#pragma unroll
    for (int g = 0; g < 4; g++) mrow4[g] = mrow[q * 4 + g];

#pragma unroll
    for (int tt = 0; tt < MAXT; tt++) {
        int jt = wave + tt * 8;
        bool valid = (jt < tiles);
        int jts = valid ? jt : 0;
        int c = tilec[jts];
        int jb = jts * 64;
        const unsigned short* qa = &qloc[c][m][q * 8];
        bf16x8 a0 = *(const bf16x8*)qa;
        bf16x8 a1 = *(const bf16x8*)(qa + 32);
        bf16x8 kreg[8];
        int mj4[4];
#pragma unroll
        for (int nb = 0; nb < 4; nb++) {
            int j = jb + nb * 16 + m;
            const unsigned short* kb = &KbB[(size_t)j * 64 + q * 8];
            kreg[nb * 2]     = *(const bf16x8*)kb;
            kreg[nb * 2 + 1] = *(const bf16x8*)(kb + 32);
            mj4[nb] = maskPB[j];
        }
#pragma unroll
        for (int nb = 0; nb < 4; nb++) {
            f32x4 acc = {0.f, 0.f, 0.f, 0.f};
            acc = __builtin_amdgcn_mfma_f32_16x16x32_bf16(a0, kreg[nb * 2], acc, 0, 0, 0);
            acc = __builtin_amdgcn_mfma_f32_16x16x32_bf16(a1, kreg[nb * 2 + 1], acc, 0, 0, 0);
            int mj = mj4[nb];
#pragma unroll
            for (int g = 0; g < 4; g++) {
                float sv;
                if (!valid || mj == 2)   sv = -INFINITY;      // padding / no tile
                else if (mrow4[g] && mj) sv = acc[g] * 0.125f;
                else                     sv = -1e30f;         // reference's masked value
                sarr[tt][nb][g] = sv;
                lmax[g] = fmaxf(lmax[g], sv);
            }
        }
    }
#pragma unroll
    for (int g = 0; g < 4; g++) {
        float v = lmax[g];
#pragma unroll
        for (int o = 1; o < 16; o <<= 1) v = fmaxf(v, __shfl_xor(v, o));
        lmax[g] = v;
    }
    if (m == 0) {
#pragma unroll
        for (int g = 0; g < 4; g++) wred[wave][q * 4 + g] = lmax[g];
    }
    __syncthreads();   // qloc dead from here

    // ---- phase 2: exp in regs, single P write into S, row sums (normalization deferred)
    float mx4[4], lsum[4] = {0.f, 0.f, 0.f, 0.f};
#pragma unroll
    for (int g = 0; g < 4; g++) {
        int i = q * 4 + g;
        float v = wred[0][i];
#pragma unroll
        for (int w2 = 1; w2 < 8; w2++) v = fmaxf(v, wred[w2][i]);
        mx4[g] = v;
    }
#pragma unroll
    for (int tt = 0; tt < MAXT; tt++) {
        int jt = wave + tt * 8;
        bool valid = (jt < tiles);
        int jb = jt * 64;
#pragma unroll
        for (int nb = 0; nb < 4; nb++) {
            int j = jb + nb * 16 + m;
#pragma unroll
            for (int g = 0; g < 4; g++) {
                float p = __expf(sarr[tt][nb][g] - mx4[g]);   // -inf -> 0
                lsum[g] += p;
                if (valid) S[q * 4 + g][j] = f2bf(p);
            }
        }
    }
#pragma unroll
    for (int g = 0; g < 4; g++) {
        float v = lsum[g];
#pragma unroll
        for (int o = 1; o < 16; o <<= 1) v += __shfl_xor(v, o);
        lsum[g] = v;
    }
    if (m == 0) {
#pragma unroll
        for (int g = 0; g < 4; g++) wsum[wave][q * 4 + g] = lsum[g];
    }
    __syncthreads();

    // ---- phase 3: per-class PV into u; wave = (kw, c-half); contiguous class tile ranges
    {
        int kw = wave & 3, chalf = wave >> 2;
        int db = kw * 16;
        int cb = chalf ? 3 : 0, ce = chalf ? 5 : 3;
        for (int c = cb; c < ce; c++) {
            int ct0 = cstart[c] >> 6, ct1 = cstart[c + 1] >> 6;
            f32x4 ae = {0.f, 0.f, 0.f, 0.f};
            f32x4 ao = {0.f, 0.f, 0.f, 0.f};
            for (int jt = ct0; jt < ct1; jt++) {
                int jb = jt * 64;
                bf16x8 a0 = *(const bf16x8*)&S[m][jb + q * 8];
                bf16x8 a1 = *(const bf16x8*)&S[m][jb + 32 + q * 8];
                const unsigned short* vb = &VtB[(size_t)(db + m) * NP + jb + q * 8];
                bf16x8 b0 = *(const bf16x8*)vb;
                bf16x8 b1 = *(const bf16x8*)(vb + 32);
                ae = __builtin_amdgcn_mfma_f32_16x16x32_bf16(a0, b0, ae, 0, 0, 0);
                ao = __builtin_amdgcn_mfma_f32_16x16x32_bf16(a1, b1, ao, 0, 0, 0);
            }
#pragma unroll
            for (int g = 0; g < 4; g++)
                u[c][q * 4 + g][db + m] = f2bf(ae[g] + ao[g]);
        }
    }
    __syncthreads();   // S dead from here; pbuf region reusable

    // ---- phase 4: out = (sum_c u[c] . W2m[cls(r,c)]) ; wave = (kw, c-half); pbuf combine
    {
        int kw = wave & 3, p = wave >> 2;
        int cb = p ? 3 : 0, ce = p ? 5 : 3;
        f32x4 acc = {0.f, 0.f, 0.f, 0.f};
        for (int c = cb; c < ce; c++) {
            int cls = clsOf(r, c);
            const unsigned short* ua = &u[c][m][q * 8];
            bf16x8 a0 = *(const bf16x8*)ua;
            bf16x8 a1 = *(const bf16x8*)(ua + 32);
            const unsigned short* wb = W2bt + (((size_t)cls * NH + h) << 12)
                                     + (size_t)(kw * 16 + m) * 64 + q * 8;
            bf16x8 b0 = *(const bf16x8*)wb;
            bf16x8 b1 = *(const bf16x8*)(wb + 32);
            acc = __builtin_amdgcn_mfma_f32_16x16x32_bf16(a0, b0, acc, 0, 0, 0);
            acc = __builtin_amdgcn_mfma_f32_16x16x32_bf16(a1, b1, acc, 0, 0, 0);
        }
#pragma unroll
        for (int g = 0; g < 4; g++)
            pbuf[p][q * 4 + g][kw * 16 + m] = acc[g];
    }
    __syncthreads();

    // ---- epilogue: combine halves, normalize, store
    for (int idx = tid; idx < 16 * 64; idx += 512) {
        int i = idx >> 6, k = idx & 63;
        int tok = toki[i];
        if (tok >= 0) {
            float s = wsum[0][i] + wsum[1][i] + wsum[2][i] + wsum[3][i]
                    + wsum[4][i] + wsum[5][i] + wsum[6][i] + wsum[7][i];
            float v = pbuf[0][i][k] + pbuf[1][i][k];
            out[((size_t)b * NN + tok) * (NH * DKK) + h * DKK + k] = v / s;
        }
    }
}

// ---------------------------------------------------------------- launch
extern "C" void kernel_launch(void* const* d_in, const int* in_sizes, int n_in,
                              void* d_out, int out_size, void* d_ws, size_t ws_size,
                              hipStream_t stream)
{
    const float* qr  = (const float*)d_in[0];
    const float* kr  = (const float*)d_in[1];
    const float* vr  = (const float*)d_in[2];
    const void* bsr  = d_in[3];
    const void* mkr  = d_in[4];
    const float* lr  = (const float*)d_in[5];
    const float* w1r = (const float*)d_in[6];
    const float* a1r = (const float*)d_in[7];
    const float* w2r = (const float*)d_in[8];
    const float* a2r = (const float*)d_in[9];
    float* out = (float*)d_out;

    char* w = (char*)d_ws;
    int* maskI    = (int*)w;
    int* perm     = maskI + BQ * NN;
    int* rowc     = perm + BQ * NP;
    int* startPad = rowc + BQ * NP;
    int* maskP    = startPad + 12;
    unsigned short* W1bt = (unsigned short*)(w + 65536);
    unsigned short* W2bt = W1bt + (size_t)NCLS * NH * 4096;
    unsigned short* Qb   = (unsigned short*)(w + 2359296);
    unsigned short* Kb   = Qb + (size_t)BQ * NH * NP * 64;
    unsigned short* Vt   = Kb + (size_t)BQ * NH * NP * 64;           // [b][h][d][ip]
    unsigned short* Lt   = (unsigned short*)(w + 10616832);
    unsigned short* Xc   = (unsigned short*)(w + 26345472);          // total ~32.6 MB

    hipLaunchKernelGGL(k_prep, dim3(960 + 2 * NCLS * NH + 96 + 1), dim3(256), 0, stream,
                       lr, Lt, w1r, w2r, a1r, a2r, W1bt, W2bt, qr, kr, vr, Xc,
                       bsr, mkr, maskI, perm, rowc, startPad, maskP);
    hipLaunchKernelGGL(k_proj, dim3(504), dim3(256), 0, stream,
                       Xc, Lt, perm, rowc, startPad, Qb, Kb, Vt);
    hipLaunchKernelGGL(k_attn, dim3(8 * 2 * 84), dim3(512), 0, stream,
                       Qb, Kb, Vt, W1bt, W2bt, perm, rowc, startPad, maskI, maskP, out);
}